// Round 6
// baseline (6090.681 us; speedup 1.0000x reference)
//
#include <hip/hip_runtime.h>
#include <cstddef>
#include <cmath>

// ---------------- problem constants ----------------
constexpr int CB  = 16;
constexpr int CS  = 128;
constexpr int CD  = 384;
constexpr int CDF = 1536;
constexpr int CH  = 2;
constexpr int CL  = 6;
constexpr int CNM = 80;
constexpr int CLOUT = 1024;
constexpr int CDH = 192;

typedef __bf16 bf16x8 __attribute__((ext_vector_type(8)));
typedef float  f32x4  __attribute__((ext_vector_type(4)));

// =====================================================================
// ======  bf16 MFMA GEMM (round-3 verified staging: padded LDS) =======
// =====================================================================
// C = scale*(A @ Bt^T) + bias + resid.  A bf16 [M,K] lda ; Bt bf16 [N,K] ldb.
// M % 128 == 0, K % 64 == 0, N arbitrary (B-rows clamped, stores masked).
constexpr int LDT = 72;   // padded LDS row stride (bf16) -> 144B, benign 2-way b128
__global__ __launch_bounds__(256) void mm_bf16(
    const __bf16* __restrict__ A, long lda, long sA1, long sA2,
    const __bf16* __restrict__ Bt, long ldb, long sB1, long sB2,
    const float* __restrict__ bias, const float* __restrict__ resid,
    void* __restrict__ Cp, long ldc, long sC1, long sC2,
    int M, int N, int K, int zdiv, int relu, int outBf, float scale)
{
    int z = blockIdx.z;
    int zb = z / zdiv, zh = z % zdiv;
    const __bf16* Ab = A  + (long)zb * sA1 + (long)zh * sA2;
    const __bf16* Bb = Bt + (long)zb * sB1 + (long)zh * sB2;
    long coff = (long)zb * sC1 + (long)zh * sC2;

    __shared__ __attribute__((aligned(16))) __bf16 As[128 * LDT];
    __shared__ __attribute__((aligned(16))) __bf16 Bs[128 * LDT];

    int tid  = threadIdx.x;
    int lane = tid & 63;
    int wave = tid >> 6;
    int quad = lane >> 4;
    int l16  = lane & 15;
    int wm = (wave >> 1) * 64;
    int wn = (wave & 1) * 64;

    int mBase = blockIdx.y * 128;
    int nBase = blockIdx.x * 128;

    int trow  = tid >> 3;        // 0..31
    int tcol8 = (tid & 7) * 8;   // element col in [0,64)

    f32x4 acc[4][4] = {};

    for (int k0 = 0; k0 < K; k0 += 64) {
#pragma unroll
        for (int p = 0; p < 4; ++p) {
            int r = p * 32 + trow;
            const __bf16* ga = Ab + (long)(mBase + r) * lda + k0 + tcol8;
            *(uint4*)(&As[r * LDT + tcol8]) = *(const uint4*)ga;
            int gn = nBase + r; gn = gn < N ? gn : N - 1;
            const __bf16* gb = Bb + (long)gn * ldb + k0 + tcol8;
            *(uint4*)(&Bs[r * LDT + tcol8]) = *(const uint4*)gb;
        }
        __syncthreads();
#pragma unroll
        for (int ks = 0; ks < 2; ++ks) {
            int kof = ks * 32 + quad * 8;
            bf16x8 af[4], bfr[4];
#pragma unroll
            for (int mt = 0; mt < 4; ++mt)
                af[mt] = *(const bf16x8*)(&As[(wm + mt * 16 + l16) * LDT + kof]);
#pragma unroll
            for (int nt = 0; nt < 4; ++nt)
                bfr[nt] = *(const bf16x8*)(&Bs[(wn + nt * 16 + l16) * LDT + kof]);
#pragma unroll
            for (int mt = 0; mt < 4; ++mt)
#pragma unroll
                for (int nt = 0; nt < 4; ++nt)
                    acc[mt][nt] = __builtin_amdgcn_mfma_f32_16x16x32_bf16(
                        af[mt], bfr[nt], acc[mt][nt], 0, 0, 0);
        }
        __syncthreads();
    }

    // epilogue: C/D layout col=lane&15, row=quad*4+reg
#pragma unroll
    for (int mt = 0; mt < 4; ++mt) {
#pragma unroll
        for (int nt = 0; nt < 4; ++nt) {
            int col = nBase + wn + nt * 16 + l16;
            if (col >= N) continue;
            int row0 = mBase + wm + mt * 16 + quad * 4;
            float bv = bias ? bias[col] : 0.f;
#pragma unroll
            for (int r = 0; r < 4; ++r) {
                long off = coff + (long)(row0 + r) * ldc + col;
                float v = acc[mt][nt][r] * scale + bv;
                if (resid) v += resid[off];
                if (relu) v = fmaxf(v, 0.f);
                if (outBf) ((__bf16*)Cp)[off] = (__bf16)v;
                else       ((float*)Cp)[off] = v;
            }
        }
    }
}

// ---- softmax in-place on bf16 rows ----
__global__ __launch_bounds__(256) void softmax_bf16(__bf16* __restrict__ buf, int T)
{
    long r = blockIdx.x;
    __bf16* row = buf + r * (long)T;
    int tid = threadIdx.x;
    int npt = (T + 255) >> 8;

    float e[8];
    float mx = -3.4e38f;
    for (int j = 0; j < npt && j < 8; ++j) {
        int i = tid + j * 256;
        e[j] = (i < T) ? (float)row[i] : -3.4e38f;
        mx = fmaxf(mx, e[j]);
    }
#pragma unroll
    for (int off = 32; off > 0; off >>= 1) mx = fmaxf(mx, __shfl_down(mx, off));
    __shared__ float sh[4];
    int wv = tid >> 6, ln = tid & 63;
    if (ln == 0) sh[wv] = mx;
    __syncthreads();
    if (tid == 0) { float m = sh[0]; for (int i = 1; i < 4; ++i) m = fmaxf(m, sh[i]); sh[0] = m; }
    __syncthreads();
    mx = sh[0];
    __syncthreads();

    float sum = 0.f;
    for (int j = 0; j < npt && j < 8; ++j) {
        int i = tid + j * 256;
        if (i < T) { e[j] = __expf(e[j] - mx); sum += e[j]; }
        else e[j] = 0.f;
    }
#pragma unroll
    for (int off = 32; off > 0; off >>= 1) sum += __shfl_down(sum, off);
    if (ln == 0) sh[wv] = sum;
    __syncthreads();
    if (tid == 0) { float s = 0.f; for (int i = 0; i < 4; ++i) s += sh[i]; sh[0] = s; }
    __syncthreads();
    float inv = 1.0f / sh[0];
    for (int j = 0; j < npt && j < 8; ++j) {
        int i = tid + j * 256;
        if (i < T) row[i] = (__bf16)(e[j] * inv);
    }
}

// ---- LN (input already has residual added): out32 = LN(a)*g+be ; bf16 padded copy ----
__global__ __launch_bounds__(CD) void ln_res(const float* __restrict__ a,
    const float* __restrict__ g, const float* __restrict__ be,
    float* __restrict__ out32, __bf16* __restrict__ outbf, int Tlog2)
{
    long r = blockIdx.x;
    int d = threadIdx.x;
    float v = a[r * CD + d];
    float s1 = v, s2 = v * v;
#pragma unroll
    for (int off = 32; off > 0; off >>= 1) {
        s1 += __shfl_down(s1, off);
        s2 += __shfl_down(s2, off);
    }
    __shared__ float sh1[CD / 64], sh2[CD / 64];
    int wv = d >> 6, ln = d & 63;
    if (ln == 0) { sh1[wv] = s1; sh2[wv] = s2; }
    __syncthreads();
    if (d == 0) {
        float t1 = 0.f, t2 = 0.f;
        for (int i = 0; i < CD / 64; ++i) { t1 += sh1[i]; t2 += sh2[i]; }
        sh1[0] = t1; sh2[0] = t2;
    }
    __syncthreads();
    float mean = sh1[0] * (1.0f / CD);
    float var  = sh2[0] * (1.0f / CD) - mean * mean;
    float res = (v - mean) * rsqrtf(var + 1e-5f) * g[d] + be[d];
    out32[r * CD + d] = res;
    int T = 1 << Tlog2;
    long bb = r >> Tlog2; int t = (int)(r & (T - 1));
    outbf[(bb * (T + 2) + t + 1) * CD + d] = (__bf16)res;
}

// ---- fp32 chunk -> bf16 padded ----
__global__ __launch_bounds__(CD) void f32_to_padbf16(const float* __restrict__ in,
    __bf16* __restrict__ out, int Tlog2)
{
    long r = blockIdx.x;
    int d = threadIdx.x;
    int T = 1 << Tlog2;
    long b = r >> Tlog2; int t = (int)(r & (T - 1));
    out[(b * (T + 2) + t + 1) * CD + d] = (__bf16)in[r * CD + d];
}

// ---- zero the pad rows of a padded buffer [NB][T+2][C] ----
__global__ void zero_pads(__bf16* __restrict__ p, int Tp2, int C)
{
    int b = blockIdx.x >> 1;
    int which = blockIdx.x & 1;
    long row = (long)b * Tp2 + (which ? Tp2 - 1 : 0);
    for (int c = threadIdx.x; c < C; c += blockDim.x) p[row * C + c] = (__bf16)0.f;
}

// ---- transpose fp32 [R,C] -> bf16 [C,R] ----
__global__ __launch_bounds__(256) void tr_f32_bf16(const float* __restrict__ in,
    __bf16* __restrict__ out, int R, int C)
{
    __shared__ float t[32][33];
    int c0 = blockIdx.x * 32, r0 = blockIdx.y * 32;
    int tx = threadIdx.x & 31, ty = threadIdx.x >> 5;
#pragma unroll
    for (int i = 0; i < 4; ++i) {
        int rr = ty * 4 + i;
        int r = r0 + rr, c = c0 + tx;
        if (r < R && c < C) t[rr][tx] = in[(long)r * C + c];
    }
    __syncthreads();
#pragma unroll
    for (int i = 0; i < 4; ++i) {
        int cc = ty * 4 + i;
        int c = c0 + cc, r = r0 + tx;
        if (c < C && r < R) out[(long)c * R + r] = (__bf16)t[tx][cc];
    }
}

// ---- transpose bf16, z-batched: out[c*ldout + r] = in[r*ldin + c] ----
__global__ __launch_bounds__(256) void tr_bf16(const __bf16* __restrict__ in, long ldin,
    long sI1, long sI2, __bf16* __restrict__ out, long ldout, long sO1, long sO2,
    int R, int C, int zdiv)
{
    int z = blockIdx.z;
    int zb = z / zdiv, zh = z % zdiv;
    in  += (long)zb * sI1 + (long)zh * sI2;
    out += (long)zb * sO1 + (long)zh * sO2;
    __shared__ __bf16 t[32][33];
    int c0 = blockIdx.x * 32, r0 = blockIdx.y * 32;
    int tx = threadIdx.x & 31, ty = threadIdx.x >> 5;
#pragma unroll
    for (int i = 0; i < 4; ++i) {
        int rr = ty * 4 + i;
        int r = r0 + rr, c = c0 + tx;
        if (r < R && c < C) t[rr][tx] = in[(long)r * ldin + c];
    }
    __syncthreads();
#pragma unroll
    for (int i = 0; i < 4; ++i) {
        int cc = ty * 4 + i;
        int c = c0 + cc, r = r0 + tx;
        if (c < C && r < R) out[(long)c * ldout + r] = t[tx][cc];
    }
}

// ---- conv weight [O,Cc,3] -> bf16 [O, 3*Cc] with (kk,c) order ----
__global__ void convw_bf16(const float* __restrict__ w, __bf16* __restrict__ wt,
                           int O, int Cc)
{
    long total = (long)O * 3 * Cc;
    int KC = 3 * Cc;
    for (long i = (long)blockIdx.x * blockDim.x + threadIdx.x; i < total;
         i += (long)gridDim.x * blockDim.x) {
        int j = (int)(i % KC); long o = i / KC;
        int kk = j / Cc, c = j % Cc;
        wt[i] = (__bf16)w[(o * Cc + c) * 3 + kk];
    }
}

// ---- embed + positional encoding (fp32 out) ----
__global__ __launch_bounds__(CD) void embed_pe_kernel(const int* __restrict__ x,
    const float* __restrict__ emb, float* __restrict__ h)
{
    int bs = blockIdx.x;
    int d  = threadIdx.x;
    int s  = bs & (CS - 1);
    int tok = x[bs];
    int i = d >> 1;
    float ang = (float)s * powf(10000.0f, -2.0f * (float)i / (float)CD);
    float pe = (d & 1) ? cosf(ang) : sinf(ang);
    h[(size_t)bs * CD + d] = emb[(size_t)tok * CD + d] + pe;
}

// ---- length regulation ----
__global__ __launch_bounds__(CS) void lenreg_kernel(const int* __restrict__ y,
    int* __restrict__ idx, int* __restrict__ totals)
{
    __shared__ int ends[CS];
    int b = blockIdx.x, tid = threadIdx.x;
    if (tid == 0) {
        int acc = 0;
        for (int s = 0; s < CS; ++s) { acc += y[b * CS + s]; ends[s] = acc; }
    }
    __syncthreads();
    for (int t = tid; t < CLOUT; t += CS) idx[b * CLOUT + t] = CS - 1;
    if (tid == 0) totals[b] = ends[CS - 1];
    __syncthreads();
    int st = (tid == 0) ? 0 : ends[tid - 1];
    int en = ends[tid];
    for (int t = st; t < en; ++t) idx[b * CLOUT + t] = tid;
}

// ---- gather/expand, dual output (chunk fp32 + padded bf16) ----
__global__ __launch_bounds__(CD) void gather_dual(const float* __restrict__ hph,
    const int* __restrict__ idx, const int* __restrict__ tot,
    float* __restrict__ h32, __bf16* __restrict__ hbf, int chunkBase)
{
    int rl = blockIdx.x;
    int rg = chunkBase + rl;
    int b = rg >> 10, t = rg & (CLOUT - 1);
    int d = threadIdx.x;
    int src = idx[rg];
    float v = (t < tot[b]) ? hph[((long)b * CS + src) * CD + d] : 0.f;
    h32[(long)rl * CD + d] = v;
    long bl = rl >> 10; int tl = rl & (CLOUT - 1);
    hbf[(bl * (CLOUT + 2) + tl + 1) * CD + d] = (__bf16)v;
}

// =====================================================================
// ===============  OLD fp32 FALLBACK PATH (round-2, verified) =========
// =====================================================================

constexpr int TS = 64;
constexpr int KT = 16;

__global__ __launch_bounds__(256) void gemm_nn(
    const float* __restrict__ A, int lda, long sA1, long sA2,
    const float* __restrict__ W, int ldw, long sW1, long sW2,
    const float* __restrict__ bias,
    float* __restrict__ C, int ldc, long sC1, long sC2,
    int M, int N, int Kd, int zdiv, int relu, float scale)
{
    int z = blockIdx.z;
    int zb = z / zdiv, zh = z % zdiv;
    A += (long)zb * sA1 + (long)zh * sA2;
    W += (long)zb * sW1 + (long)zh * sW2;
    C += (long)zb * sC1 + (long)zh * sC2;
    __shared__ float As[TS][KT + 1];
    __shared__ float Ws[KT][TS];
    int tx = threadIdx.x, ty = threadIdx.y;
    int tid = ty * 16 + tx;
    int mBase = blockIdx.y * TS, nBase = blockIdx.x * TS;
    float acc[4][4] = {};
    for (int k0 = 0; k0 < Kd; k0 += KT) {
#pragma unroll
        for (int l = 0; l < 4; ++l) {
            int o = tid + l * 256;
            int kc = o & 15, mm = o >> 4;
            int gr = mBase + mm, gk = k0 + kc;
            As[mm][kc] = (gr < M && gk < Kd) ? A[(long)gr * lda + gk] : 0.f;
        }
#pragma unroll
        for (int l = 0; l < 4; ++l) {
            int o = tid + l * 256;
            int nn = o & 63, kc = o >> 6;
            int gk = k0 + kc, gc = nBase + nn;
            Ws[kc][nn] = (gk < Kd && gc < N) ? W[(long)gk * ldw + gc] : 0.f;
        }
        __syncthreads();
#pragma unroll
        for (int kc = 0; kc < KT; ++kc) {
            float a[4], bb[4];
#pragma unroll
            for (int i = 0; i < 4; ++i) a[i] = As[ty * 4 + i][kc];
#pragma unroll
            for (int j = 0; j < 4; ++j) bb[j] = Ws[kc][tx * 4 + j];
#pragma unroll
            for (int i = 0; i < 4; ++i)
#pragma unroll
                for (int j = 0; j < 4; ++j)
                    acc[i][j] = fmaf(a[i], bb[j], acc[i][j]);
        }
        __syncthreads();
    }
#pragma unroll
    for (int i = 0; i < 4; ++i) {
        int r = mBase + ty * 4 + i;
        if (r >= M) continue;
#pragma unroll
        for (int j = 0; j < 4; ++j) {
            int c = nBase + tx * 4 + j;
            if (c >= N) continue;
            float v = acc[i][j] * scale + (bias ? bias[c] : 0.f);
            if (relu) v = fmaxf(v, 0.f);
            C[(long)r * ldc + c] = v;
        }
    }
}

__global__ __launch_bounds__(256) void gemm_nt(
    const float* __restrict__ A, int lda, long sA1, long sA2,
    const float* __restrict__ Bm, int ldb, long sB1, long sB2,
    float* __restrict__ C, int ldc, long sC1, long sC2,
    int M, int N, int Kd, int zdiv, float scale)
{
    int z = blockIdx.z;
    int zb = z / zdiv, zh = z % zdiv;
    A  += (long)zb * sA1 + (long)zh * sA2;
    Bm += (long)zb * sB1 + (long)zh * sB2;
    C  += (long)zb * sC1 + (long)zh * sC2;
    __shared__ float As[TS][KT + 1];
    __shared__ float Bs[TS][KT + 1];
    int tx = threadIdx.x, ty = threadIdx.y;
    int tid = ty * 16 + tx;
    int mBase = blockIdx.y * TS, nBase = blockIdx.x * TS;
    float acc[4][4] = {};
    for (int k0 = 0; k0 < Kd; k0 += KT) {
#pragma unroll
        for (int l = 0; l < 4; ++l) {
            int o = tid + l * 256;
            int kc = o & 15, mm = o >> 4;
            int gr = mBase + mm, gk = k0 + kc;
            As[mm][kc] = (gr < M && gk < Kd) ? A[(long)gr * lda + gk] : 0.f;
        }
#pragma unroll
        for (int l = 0; l < 4; ++l) {
            int o = tid + l * 256;
            int kc = o & 15, nn = o >> 4;
            int gn = nBase + nn, gk = k0 + kc;
            Bs[nn][kc] = (gn < N && gk < Kd) ? Bm[(long)gn * ldb + gk] : 0.f;
        }
        __syncthreads();
#pragma unroll
        for (int kc = 0; kc < KT; ++kc) {
            float a[4], bb[4];
#pragma unroll
            for (int i = 0; i < 4; ++i) a[i] = As[ty * 4 + i][kc];
#pragma unroll
            for (int j = 0; j < 4; ++j) bb[j] = Bs[tx * 4 + j][kc];
#pragma unroll
            for (int i = 0; i < 4; ++i)
#pragma unroll
                for (int j = 0; j < 4; ++j)
                    acc[i][j] = fmaf(a[i], bb[j], acc[i][j]);
        }
        __syncthreads();
    }
#pragma unroll
    for (int i = 0; i < 4; ++i) {
        int r = mBase + ty * 4 + i;
        if (r >= M) continue;
#pragma unroll
        for (int j = 0; j < 4; ++j) {
            int c = nBase + tx * 4 + j;
            if (c >= N) continue;
            C[(long)r * ldc + c] = acc[i][j] * scale;
        }
    }
}

__global__ __launch_bounds__(256) void conv_k3(
    const float* __restrict__ A, const float* __restrict__ Wt,
    const float* __restrict__ bias, float* __restrict__ Cout,
    int T, int tshift, int Cc, int O, int M, int relu)
{
    __shared__ float As[3][TS][KT + 1];
    __shared__ float Ws[3][KT][TS];
    int tx = threadIdx.x, ty = threadIdx.y;
    int tid = ty * 16 + tx;
    int mBase = blockIdx.y * TS, nBase = blockIdx.x * TS;
    float acc[4][4] = {};
    for (int k0 = 0; k0 < Cc; k0 += KT) {
#pragma unroll
        for (int kk = 0; kk < 3; ++kk) {
#pragma unroll
            for (int l = 0; l < 4; ++l) {
                int o = tid + l * 256;
                int kc = o & 15, mm = o >> 4;
                int gr = mBase + mm;
                int b = gr >> tshift, t = gr & (T - 1);
                int ts = t + kk - 1;
                float v = 0.f;
                if (gr < M && ts >= 0 && ts < T)
                    v = A[((long)(b << tshift) + ts) * Cc + k0 + kc];
                As[kk][mm][kc] = v;
            }
#pragma unroll
            for (int l = 0; l < 4; ++l) {
                int o = tid + l * 256;
                int nn = o & 63, kc = o >> 6;
                int gc = nBase + nn;
                Ws[kk][kc][nn] = (gc < O) ? Wt[((long)kk * Cc + k0 + kc) * O + gc] : 0.f;
            }
        }
        __syncthreads();
#pragma unroll
        for (int kk = 0; kk < 3; ++kk) {
#pragma unroll
            for (int kc = 0; kc < KT; ++kc) {
                float a[4], bb[4];
#pragma unroll
                for (int i = 0; i < 4; ++i) a[i] = As[kk][ty * 4 + i][kc];
#pragma unroll
                for (int j = 0; j < 4; ++j) bb[j] = Ws[kk][kc][tx * 4 + j];
#pragma unroll
                for (int i = 0; i < 4; ++i)
#pragma unroll
                    for (int j = 0; j < 4; ++j)
                        acc[i][j] = fmaf(a[i], bb[j], acc[i][j]);
            }
        }
        __syncthreads();
    }
#pragma unroll
    for (int i = 0; i < 4; ++i) {
        int r = mBase + ty * 4 + i;
        if (r >= M) continue;
#pragma unroll
        for (int j = 0; j < 4; ++j) {
            int c = nBase + tx * 4 + j;
            if (c >= O) continue;
            float v = acc[i][j] + bias[c];
            if (relu) v = fmaxf(v, 0.f);
            Cout[(long)r * O + c] = v;
        }
    }
}

__global__ void transpose_w(const float* __restrict__ W, float* __restrict__ Wt,
                            int Cc, int O)
{
    int total = 3 * Cc * O;
    for (int i = blockIdx.x * blockDim.x + threadIdx.x; i < total;
         i += gridDim.x * blockDim.x) {
        int o = i % O; int rest = i / O; int c = rest % Cc; int kk = rest / Cc;
        Wt[i] = W[((long)o * Cc + c) * 3 + kk];
    }
}

__global__ __launch_bounds__(CD) void ln_kernel(const float* __restrict__ a,
    const float* __restrict__ bsrc, const float* __restrict__ g,
    const float* __restrict__ be, float* __restrict__ out)
{
    long r = blockIdx.x;
    int d = threadIdx.x;
    float v = a[r * CD + d] + bsrc[r * CD + d];
    float s1 = v, s2 = v * v;
#pragma unroll
    for (int off = 32; off > 0; off >>= 1) {
        s1 += __shfl_down(s1, off);
        s2 += __shfl_down(s2, off);
    }
    __shared__ float sh1[CD / 64], sh2[CD / 64];
    int wv = d >> 6, ln = d & 63;
    if (ln == 0) { sh1[wv] = s1; sh2[wv] = s2; }
    __syncthreads();
    if (d == 0) {
        float t1 = 0.f, t2 = 0.f;
        for (int i = 0; i < CD / 64; ++i) { t1 += sh1[i]; t2 += sh2[i]; }
        sh1[0] = t1; sh2[0] = t2;
    }
    __syncthreads();
    float mean = sh1[0] * (1.0f / CD);
    float var  = sh2[0] * (1.0f / CD) - mean * mean;
    out[r * CD + d] = (v - mean) * rsqrtf(var + 1e-5f) * g[d] + be[d];
}

__global__ __launch_bounds__(256) void softmax_rows(float* __restrict__ sc, int T)
{
    long r = blockIdx.x;
    float* row = sc + r * (long)T;
    int tid = threadIdx.x;
    float mx = -3.4e38f;
    for (int i = tid; i < T; i += 256) mx = fmaxf(mx, row[i]);
#pragma unroll
    for (int off = 32; off > 0; off >>= 1) mx = fmaxf(mx, __shfl_down(mx, off));
    __shared__ float sh[4];
    int wv = tid >> 6, ln = tid & 63;
    if (ln == 0) sh[wv] = mx;
    __syncthreads();
    if (tid == 0) { float m = sh[0]; for (int i = 1; i < 4; ++i) m = fmaxf(m, sh[i]); sh[0] = m; }
    __syncthreads();
    mx = sh[0];
    __syncthreads();
    float sum = 0.f;
    for (int i = tid; i < T; i += 256) {
        float e = __expf(row[i] - mx);
        row[i] = e;
        sum += e;
    }
#pragma unroll
    for (int off = 32; off > 0; off >>= 1) sum += __shfl_down(sum, off);
    if (ln == 0) sh[wv] = sum;
    __syncthreads();
    if (tid == 0) { float s = 0.f; for (int i = 0; i < 4; ++i) s += sh[i]; sh[0] = s; }
    __syncthreads();
    float inv = 1.0f / sh[0];
    for (int i = tid; i < T; i += 256) row[i] *= inv;
}

__global__ __launch_bounds__(CD) void gather_expand(const float* __restrict__ h,
    const int* __restrict__ idx, const int* __restrict__ totals,
    float* __restrict__ out)
{
    int r = blockIdx.x;
    int b = r >> 10, t = r & (CLOUT - 1);
    int d = threadIdx.x;
    int src = idx[r];
    float v = (t < totals[b]) ? h[((long)b * CS + src) * CD + d] : 0.f;
    out[(long)r * CD + d] = v;
}

static inline void launch_nn(hipStream_t st,
    const float* A, int lda, long sA1, long sA2,
    const float* W, int ldw, long sW1, long sW2, const float* bias,
    float* C, int ldc, long sC1, long sC2,
    int M, int N, int Kd, int nz, int zdiv, int relu, float scale)
{
    dim3 g((N + TS - 1) / TS, (M + TS - 1) / TS, nz), b(16, 16, 1);
    hipLaunchKernelGGL(gemm_nn, g, b, 0, st, A, lda, sA1, sA2, W, ldw, sW1, sW2,
                       bias, C, ldc, sC1, sC2, M, N, Kd, zdiv, relu, scale);
}

static inline void launch_nt(hipStream_t st,
    const float* A, int lda, long sA1, long sA2,
    const float* Bm, int ldb, long sB1, long sB2,
    float* C, int ldc, long sC1, long sC2,
    int M, int N, int Kd, int nz, int zdiv, float scale)
{
    dim3 g((N + TS - 1) / TS, (M + TS - 1) / TS, nz), b(16, 16, 1);
    hipLaunchKernelGGL(gemm_nt, g, b, 0, st, A, lda, sA1, sA2, Bm, ldb, sB1, sB2,
                       C, ldc, sC1, sC2, M, N, Kd, zdiv, scale);
}

static void fft_chunk_f32(hipStream_t st, float* hch, int NBc, int T, int tshift,
    float* x_c, float* qkv_c, float* o_c, float* t_c, float* s_c,
    const float* wt1, const float* wt2,
    const float* qkv_w, const float* qkv_b, const float* out_w, const float* out_b,
    const float* g1, const float* b1, const float* c1b, const float* c2b,
    const float* g2, const float* b2)
{
    const int M = NBc * T;
    const float scl = 1.0f / sqrtf((float)CDH);
    launch_nn(st, hch, CD, 0, 0, qkv_w, 3 * CD, 0, 0, qkv_b,
              qkv_c, 3 * CD, 0, 0, M, 3 * CD, CD, 1, 1, 0, 1.f);
    launch_nt(st, qkv_c, 3 * CD, (long)T * 3 * CD, CDH,
              qkv_c + CD, 3 * CD, (long)T * 3 * CD, CDH,
              s_c, T, (long)CH * T * T, (long)T * T,
              T, T, CDH, NBc * CH, CH, scl);
    hipLaunchKernelGGL(softmax_rows, dim3(NBc * CH * T), dim3(256), 0, st, s_c, T);
    launch_nn(st, s_c, T, (long)CH * T * T, (long)T * T,
              qkv_c + 2 * CD, 3 * CD, (long)T * 3 * CD, CDH, nullptr,
              o_c, CD, (long)T * CD, CDH,
              T, CDH, T, NBc * CH, CH, 0, 1.f);
    launch_nn(st, o_c, CD, 0, 0, out_w, CD, 0, 0, out_b,
              t_c, CD, 0, 0, M, CD, CD, 1, 1, 0, 1.f);
    hipLaunchKernelGGL(ln_kernel, dim3(M), dim3(CD), 0, st, t_c, hch, g1, b1, x_c);
    hipLaunchKernelGGL(conv_k3, dim3(CDF / TS, M / TS), dim3(16, 16), 0, st,
                       x_c, wt1, c1b, s_c, T, tshift, CD, CDF, M, 1);
    hipLaunchKernelGGL(conv_k3, dim3(CD / TS, M / TS), dim3(16, 16), 0, st,
                       s_c, wt2, c2b, t_c, T, tshift, CDF, CD, M, 0);
    hipLaunchKernelGGL(ln_kernel, dim3(M), dim3(CD), 0, st, t_c, x_c, g2, b2, hch);
}

static void run_fp32_path(void* const* d_in, int n_in, void* d_out, void* d_ws,
                          size_t ws_size, hipStream_t stream)
{
    const int* x = (const int*)d_in[0];
    const int* y = (const int*)d_in[1];
    const float* P[40];
    for (int i = 0; i < n_in && i < 40; ++i) P[i] = (const float*)d_in[i];

    constexpr long E_HMEL = (long)CB * CLOUT * CD;
    constexpr long E_HPH  = (long)CB * CS * CD;
    constexpr long E_WT   = 3L * CD * CDF;
    constexpr long E_IDX  = (long)CB * CLOUT + CB;
    constexpr long E_PB   = 4456448L;
    const long fixedElems = E_HMEL + E_HPH + 2 * E_WT + E_IDX;

    int NB = 1;
    for (int cand = 16; cand >= 1; cand >>= 1) {
        long tot = fixedElems + (long)cand * E_PB;
        if ((size_t)tot * sizeof(float) <= ws_size) { NB = cand; break; }
    }

    float* ws   = (float*)d_ws;
    long off = 0;
    float* hMel = ws + off; off += E_HMEL;
    float* hPh  = ws + off; off += E_HPH;
    float* wt1  = ws + off; off += E_WT;
    float* wt2  = ws + off; off += E_WT;
    int*   idxb = (int*)(ws + off); off += E_IDX;
    int*   totb = idxb + (long)CB * CLOUT;
    float* xc   = ws + off; off += (long)NB * CLOUT * CD;
    float* qkvc = ws + off; off += (long)NB * CLOUT * 3 * CD;
    float* oc   = ws + off; off += (long)NB * CLOUT * CD;
    float* tc   = ws + off; off += (long)NB * CLOUT * CD;
    float* sc   = ws + off;

    hipLaunchKernelGGL(embed_pe_kernel, dim3(CB * CS), dim3(CD), 0, stream, x, P[2], hPh);
    for (int l = 0; l < CL; ++l) {
        hipLaunchKernelGGL(transpose_w, dim3(256), dim3(256), 0, stream,
                           P[9]  + (long)l * CDF * CD * 3, wt1, CD, CDF);
        hipLaunchKernelGGL(transpose_w, dim3(256), dim3(256), 0, stream,
                           P[11] + (long)l * CD * CDF * 3, wt2, CDF, CD);
        for (int c = 0; c < CB / NB; ++c)
            fft_chunk_f32(stream, hPh + (long)c * NB * CS * CD, NB, CS, 7,
                          xc, qkvc, oc, tc, sc, wt1, wt2,
                          P[3] + (long)l * CD * 3 * CD, P[4] + (long)l * 3 * CD,
                          P[5] + (long)l * CD * CD, P[6] + (long)l * CD,
                          P[7] + (long)l * CD, P[8] + (long)l * CD,
                          P[10] + (long)l * CDF, P[12] + (long)l * CD,
                          P[13] + (long)l * CD, P[14] + (long)l * CD);
    }
    hipLaunchKernelGGL(lenreg_kernel, dim3(CB), dim3(CS), 0, stream, y, idxb, totb);
    hipLaunchKernelGGL(gather_expand, dim3(CB * CLOUT), dim3(CD), 0, stream,
                       hPh, idxb, totb, hMel);
    for (int l = 0; l < CL; ++l) {
        hipLaunchKernelGGL(transpose_w, dim3(256), dim3(256), 0, stream,
                           P[21] + (long)l * CDF * CD * 3, wt1, CD, CDF);
        hipLaunchKernelGGL(transpose_w, dim3(256), dim3(256), 0, stream,
                           P[23] + (long)l * CD * CDF * 3, wt2, CDF, CD);
        for (int c = 0; c < CB / NB; ++c)
            fft_chunk_f32(stream, hMel + (long)c * NB * CLOUT * CD, NB, CLOUT, 10,
                          xc, qkvc, oc, tc, sc, wt1, wt2,
                          P[15] + (long)l * CD * 3 * CD, P[16] + (long)l * 3 * CD,
                          P[17] + (long)l * CD * CD, P[18] + (long)l * CD,
                          P[19] + (long)l * CD, P[20] + (long)l * CD,
                          P[22] + (long)l * CDF, P[24] + (long)l * CD,
                          P[25] + (long)l * CD, P[26] + (long)l * CD);
    }
    launch_nn(stream, hMel, CD, 0, 0, P[37], CNM, 0, 0, P[38],
              (float*)d_out, CNM, 0, 0, CB * CLOUT, CNM, CD, 1, 1, 0, 1.f);
}

// =====================================================================
// ===============  bf16 path driver  ==================================
// =====================================================================

static inline void mm(hipStream_t st, const __bf16* A, long lda, long sA1, long sA2,
    const __bf16* Bt, long ldb, long sB1, long sB2, const float* bias,
    const float* resid, void* C, long ldc, long sC1, long sC2, int M, int N, int K,
    int nz, int zdiv, int relu, int outBf, float scale)
{
    dim3 g((N + 127) / 128, M / 128, nz), b(256, 1, 1);
    hipLaunchKernelGGL(mm_bf16, g, b, 0, st, A, lda, sA1, sA2, Bt, ldb, sB1, sB2,
                       bias, resid, C, ldc, sC1, sC2, M, N, K, zdiv, relu, outBf, scale);
}

struct Scr {
    float *h32, *x32, *tmp32;
    __bf16 *scb, *hbf, *xbf, *qkv, *vt, *c1p, *o;
};

static size_t scr_layout(char* base, int NB, int T, Scr* s)
{
    auto align = [](size_t v) { return (v + 255) & ~(size_t)255; };
    size_t off = 0;
    long Tp2 = T + 2;
    if (s) s->h32 = (float*)(base + off);
    off = align(off + (size_t)NB * T * CD * 4);
    if (s) s->x32 = (float*)(base + off);
    off = align(off + (size_t)NB * T * CD * 4);
    if (s) s->tmp32 = (float*)(base + off);
    off = align(off + (size_t)NB * T * CD * 4);
    if (s) s->scb = (__bf16*)(base + off);
    off = align(off + (size_t)NB * CH * T * T * 2);
    if (s) s->hbf = (__bf16*)(base + off);
    off = align(off + (size_t)NB * Tp2 * CD * 2);
    if (s) s->xbf = (__bf16*)(base + off);
    off = align(off + (size_t)NB * Tp2 * CD * 2);
    if (s) s->qkv = (__bf16*)(base + off);
    off = align(off + (size_t)NB * T * 3 * CD * 2);
    if (s) s->vt = (__bf16*)(base + off);
    off = align(off + (size_t)NB * CH * CDH * T * 2);
    if (s) s->c1p = (__bf16*)(base + off);
    off = align(off + (size_t)NB * Tp2 * CDF * 2);
    if (s) s->o = (__bf16*)(base + off);
    off = align(off + (size_t)NB * T * CD * 2);
    return off;
}

// per-layer bf16 weight offsets (elements)
constexpr long W_QKV = 0;
constexpr long W_OUT = 442368;       // 1152*384
constexpr long W_C1  = 589824;       // + 384*384
constexpr long W_C2  = 2359296;      // + 1536*1152
constexpr long WLAYER = 4128768;     // + 384*4608
constexpr long WSTACK = 6 * WLAYER;
constexpr long WTOT   = WSTACK + 30720;  // + proj 80*384

static void convert_stack_weights(hipStream_t st, __bf16* wbuf,
    const float* qkv_w, const float* out_w, const float* c1w, const float* c2w)
{
    for (int l = 0; l < CL; ++l) {
        __bf16* wl = wbuf + (long)l * WLAYER;
        hipLaunchKernelGGL(tr_f32_bf16, dim3(36, 12), dim3(256), 0, st,
                           qkv_w + (long)l * CD * 3 * CD, wl + W_QKV, CD, 3 * CD);
        hipLaunchKernelGGL(tr_f32_bf16, dim3(12, 12), dim3(256), 0, st,
                           out_w + (long)l * CD * CD, wl + W_OUT, CD, CD);
        hipLaunchKernelGGL(convw_bf16, dim3(2048), dim3(256), 0, st,
                           c1w + (long)l * CDF * CD * 3, wl + W_C1, CDF, CD);
        hipLaunchKernelGGL(convw_bf16, dim3(2048), dim3(256), 0, st,
                           c2w + (long)l * CD * CDF * 3, wl + W_C2, CD, CDF);
    }
}

static void fft_block_bf16(hipStream_t st, const Scr& S, int NBc, int T, int tlog2,
    float* h32, const __bf16* wl,
    const float* qkv_b, const float* out_b,
    const float* g1, const float* b1, const float* c1b, const float* c2b,
    const float* g2, const float* b2)
{
    const int M = NBc * T;
    const long Tp2 = T + 2;
    const float scl = 1.0f / sqrtf((float)CDH);

    // qkv = h @ Wqkv + b   (A = padded h_bf, z over batches)
    mm(st, S.hbf + CD, CD, Tp2 * CD, 0, wl + W_QKV, CD, 0, 0, qkv_b, nullptr,
       S.qkv, 3 * CD, (long)T * 3 * CD, 0, T, 3 * CD, CD, NBc, 1, 0, 1, 1.f);

    // Vt[bh][dh][t] = V
    hipLaunchKernelGGL(tr_bf16, dim3(CDH / 32, T / 32, NBc * CH), dim3(256), 0, st,
                       S.qkv + 2 * CD, 3 * CD, (long)T * 3 * CD, (long)CDH,
                       S.vt, T, (long)CH * CDH * T, (long)CDH * T,
                       T, CDH, CH);

    // scores = scl * Q @ K^T  -> bf16
    mm(st, S.qkv, 3 * CD, (long)T * 3 * CD, CDH,
       S.qkv + CD, 3 * CD, (long)T * 3 * CD, CDH, nullptr, nullptr,
       S.scb, T, (long)CH * T * T, (long)T * T,
       T, T, CDH, NBc * CH, CH, 0, 1, scl);

    // softmax in-place (bf16)
    hipLaunchKernelGGL(softmax_bf16, dim3(NBc * CH * T), dim3(256), 0, st, S.scb, T);

    // o = P @ V   (A = bf16 P, Bt = Vt)
    mm(st, S.scb, T, (long)CH * T * T, (long)T * T,
       S.vt, T, (long)CH * CDH * T, (long)CDH * T, nullptr, nullptr,
       S.o, CD, (long)T * CD, CDH,
       T, CDH, T, NBc * CH, CH, 0, 1, 1.f);

    // tmp = o @ Wout + b + h (residual fused)
    mm(st, S.o, CD, 0, 0, wl + W_OUT, CD, 0, 0, out_b, h32,
       S.tmp32, CD, 0, 0, M, CD, CD, 1, 1, 0, 0, 1.f);

    // x = LN(tmp) -> x32 + xbf(padded)
    hipLaunchKernelGGL(ln_res, dim3(M), dim3(CD), 0, st,
                       S.tmp32, g1, b1, S.x32, S.xbf, tlog2);

    // conv1: relu(x * W1) -> c1p rows 1..T (bf16)
    mm(st, S.xbf, CD, Tp2 * CD, 0, wl + W_C1, 3 * CD, 0, 0, c1b, nullptr,
       (void*)(S.c1p + CDF), CDF, Tp2 * CDF, 0,
       T, CDF, 3 * CD, NBc, 1, 1, 1, 1.f);

    // tmp = conv2 + x (residual fused)
    mm(st, S.c1p, CDF, Tp2 * CDF, 0, wl + W_C2, 3 * CDF, 0, 0, c2b, S.x32,
       S.tmp32, CD, (long)T * CD, 0,
       T, CD, 3 * CDF, NBc, 1, 0, 0, 1.f);

    // h = LN(tmp) -> h32 + hbf(padded)
    hipLaunchKernelGGL(ln_res, dim3(M), dim3(CD), 0, st,
                       S.tmp32, g2, b2, h32, S.hbf, tlog2);
}

extern "C" void kernel_launch(void* const* d_in, const int* in_sizes, int n_in,
                              void* d_out, int out_size, void* d_ws, size_t ws_size,
                              hipStream_t stream)
{
    (void)in_sizes; (void)out_size;

    const int* x = (const int*)d_in[0];
    const int* y = (const int*)d_in[1];
    const float* P[40];
    for (int i = 0; i < n_in && i < 40; ++i) P[i] = (const float*)d_in[i];

    // fixed region: bf16 weights + hPh fp32 + idx
    size_t wbufB  = ((size_t)WTOT * 2 + 255) & ~(size_t)255;
    size_t hphB   = ((size_t)CB * CS * CD * 4 + 255) & ~(size_t)255;
    size_t idxB   = (((size_t)CB * CLOUT + CB) * 4 + 255) & ~(size_t)255;
    size_t fixedB = wbufB + hphB + idxB;

    size_t scrB = (ws_size > fixedB) ? (ws_size - fixedB) : 0;

    int NBmel = 0;
    for (int cand = 16; cand >= 1; cand >>= 1)
        if (scr_layout(nullptr, cand, CLOUT, nullptr) <= scrB) { NBmel = cand; break; }
    if (NBmel == 0) { run_fp32_path(d_in, n_in, d_out, d_ws, ws_size, stream); return; }

    int NBph = 1;
    for (int cand = 16; cand >= 1; cand >>= 1)
        if (scr_layout(nullptr, cand, CS, nullptr) <= scrB) { NBph = cand; break; }

    char* base = (char*)d_ws;
    __bf16* wbuf = (__bf16*)base;
    float*  hPh  = (float*)(base + wbufB);
    int*    idxb = (int*)(base + wbufB + hphB);
    int*    totb = idxb + (long)CB * CLOUT;
    char*   scrbase = base + fixedB;

    // ================= phoneme encoder =================
    convert_stack_weights(stream, wbuf, P[3], P[5], P[9], P[11]);

    Scr Sp; scr_layout(scrbase, NBph, CS, &Sp);
    hipLaunchKernelGGL(zero_pads, dim3(NBph * 2), dim3(256), 0, stream, Sp.hbf, CS + 2, CD);
    hipLaunchKernelGGL(zero_pads, dim3(NBph * 2), dim3(256), 0, stream, Sp.xbf, CS + 2, CD);
    hipLaunchKernelGGL(zero_pads, dim3(NBph * 2), dim3(256), 0, stream, Sp.c1p, CS + 2, CDF);

    hipLaunchKernelGGL(embed_pe_kernel, dim3(CB * CS), dim3(CD), 0, stream, x, P[2], hPh);

    for (int c = 0; c < CB / NBph; ++c) {
        float* hch = hPh + (long)c * NBph * CS * CD;
        hipLaunchKernelGGL(f32_to_padbf16, dim3(NBph * CS), dim3(CD), 0, stream,
                           hch, Sp.hbf, 7);
        for (int l = 0; l < CL; ++l)
            fft_block_bf16(stream, Sp, NBph, CS, 7, hch, wbuf + (long)l * WLAYER,
                           P[4] + (long)l * 3 * CD, P[6] + (long)l * CD,
                           P[7] + (long)l * CD, P[8] + (long)l * CD,
                           P[10] + (long)l * CDF, P[12] + (long)l * CD,
                           P[13] + (long)l * CD, P[14] + (long)l * CD);
    }

    // ================= length regulation =================
    hipLaunchKernelGGL(lenreg_kernel, dim3(CB), dim3(CS), 0, stream, y, idxb, totb);

    // ================= mel decoder =================
    convert_stack_weights(stream, wbuf, P[15], P[17], P[21], P[23]);
    hipLaunchKernelGGL(tr_f32_bf16, dim3(3, 12), dim3(256), 0, stream,
                       P[37], wbuf + WSTACK, CD, CNM);

    Scr Sm; scr_layout(scrbase, NBmel, CLOUT, &Sm);
    hipLaunchKernelGGL(zero_pads, dim3(NBmel * 2), dim3(256), 0, stream, Sm.hbf, CLOUT + 2, CD);
    hipLaunchKernelGGL(zero_pads, dim3(NBmel * 2), dim3(256), 0, stream, Sm.xbf, CLOUT + 2, CD);
    hipLaunchKernelGGL(zero_pads, dim3(NBmel * 2), dim3(256), 0, stream, Sm.c1p, CLOUT + 2, CDF);

    for (int c = 0; c < CB / NBmel; ++c) {
        hipLaunchKernelGGL(gather_dual, dim3(NBmel * CLOUT), dim3(CD), 0, stream,
                           hPh, idxb, totb, Sm.h32, Sm.hbf, c * NBmel * CLOUT);
        for (int l = 0; l < CL; ++l)
            fft_block_bf16(stream, Sm, NBmel, CLOUT, 10, Sm.h32, wbuf + (long)l * WLAYER,
                           P[16] + (long)l * 3 * CD, P[18] + (long)l * CD,
                           P[19] + (long)l * CD, P[20] + (long)l * CD,
                           P[22] + (long)l * CDF, P[24] + (long)l * CD,
                           P[25] + (long)l * CD, P[26] + (long)l * CD);
        // final projection for this chunk (A = padded h_bf from last LN)
        mm(stream, Sm.hbf + CD, CD, (long)(CLOUT + 2) * CD, 0,
           wbuf + WSTACK, CD, 0, 0, P[38], nullptr,
           (float*)d_out + (long)c * NBmel * CLOUT * CNM, CNM, (long)CLOUT * CNM, 0,
           CLOUT, CNM, CD, NBmel, 1, 0, 0, 1.f);
    }
}

// Round 7
// 4447.951 us; speedup vs baseline: 1.3693x; 1.3693x over previous
//
#include <hip/hip_runtime.h>
#include <cstddef>
#include <cmath>

// ---------------- problem constants ----------------
constexpr int CB  = 16;
constexpr int CS  = 128;
constexpr int CD  = 384;
constexpr int CDF = 1536;
constexpr int CH  = 2;
constexpr int CL  = 6;
constexpr int CNM = 80;
constexpr int CLOUT = 1024;
constexpr int CDH = 192;

typedef __bf16 bf16x8 __attribute__((ext_vector_type(8)));
typedef float  f32x4  __attribute__((ext_vector_type(4)));

// =====================================================================
// ======  bf16 MFMA GEMM (round-3 verified staging: padded LDS) =======
// =====================================================================
// C = scale*(A @ Bt^T) + bias + resid.  A bf16 [M,K] lda ; Bt bf16 [N,K] ldb.
// M % 128 == 0, K % 64 == 0, N arbitrary (B-rows clamped, stores masked).
constexpr int LDT = 72;   // padded LDS row stride (bf16) -> 144B
__global__ __launch_bounds__(256) void mm_bf16(
    const __bf16* __restrict__ A, long lda, long sA1, long sA2,
    const __bf16* __restrict__ Bt, long ldb, long sB1, long sB2,
    const float* __restrict__ bias, const float* __restrict__ resid,
    void* __restrict__ Cp, long ldc, long sC1, long sC2,
    int M, int N, int K, int zdiv, int relu, int outBf, float scale)
{
    int z = blockIdx.z;
    int zb = z / zdiv, zh = z % zdiv;
    const __bf16* Ab = A  + (long)zb * sA1 + (long)zh * sA2;
    const __bf16* Bb = Bt + (long)zb * sB1 + (long)zh * sB2;
    long coff = (long)zb * sC1 + (long)zh * sC2;

    __shared__ __attribute__((aligned(16))) __bf16 As[128 * LDT];
    __shared__ __attribute__((aligned(16))) __bf16 Bs[128 * LDT];

    int tid  = threadIdx.x;
    int lane = tid & 63;
    int wave = tid >> 6;
    int quad = lane >> 4;
    int l16  = lane & 15;
    int wm = (wave >> 1) * 64;
    int wn = (wave & 1) * 64;

    int mBase = blockIdx.y * 128;
    int nBase = blockIdx.x * 128;

    int trow  = tid >> 3;        // 0..31
    int tcol8 = (tid & 7) * 8;   // element col in [0,64)

    f32x4 acc[4][4] = {};

    for (int k0 = 0; k0 < K; k0 += 64) {
#pragma unroll
        for (int p = 0; p < 4; ++p) {
            int r = p * 32 + trow;
            const __bf16* ga = Ab + (long)(mBase + r) * lda + k0 + tcol8;
            *(uint4*)(&As[r * LDT + tcol8]) = *(const uint4*)ga;
            int gn = nBase + r; gn = gn < N ? gn : N - 1;
            const __bf16* gb = Bb + (long)gn * ldb + k0 + tcol8;
            *(uint4*)(&Bs[r * LDT + tcol8]) = *(const uint4*)gb;
        }
        __syncthreads();
#pragma unroll
        for (int ks = 0; ks < 2; ++ks) {
            int kof = ks * 32 + quad * 8;
            bf16x8 af[4], bfr[4];
#pragma unroll
            for (int mt = 0; mt < 4; ++mt)
                af[mt] = *(const bf16x8*)(&As[(wm + mt * 16 + l16) * LDT + kof]);
#pragma unroll
            for (int nt = 0; nt < 4; ++nt)
                bfr[nt] = *(const bf16x8*)(&Bs[(wn + nt * 16 + l16) * LDT + kof]);
#pragma unroll
            for (int mt = 0; mt < 4; ++mt)
#pragma unroll
                for (int nt = 0; nt < 4; ++nt)
                    acc[mt][nt] = __builtin_amdgcn_mfma_f32_16x16x32_bf16(
                        af[mt], bfr[nt], acc[mt][nt], 0, 0, 0);
        }
        __syncthreads();
    }

    // epilogue: C/D layout col=lane&15, row=quad*4+reg
#pragma unroll
    for (int mt = 0; mt < 4; ++mt) {
#pragma unroll
        for (int nt = 0; nt < 4; ++nt) {
            int col = nBase + wn + nt * 16 + l16;
            if (col >= N) continue;
            int row0 = mBase + wm + mt * 16 + quad * 4;
            float bv = bias ? bias[col] : 0.f;
#pragma unroll
            for (int r = 0; r < 4; ++r) {
                long off = coff + (long)(row0 + r) * ldc + col;
                float v = acc[mt][nt][r] * scale + bv;
                if (resid) v += resid[off];
                if (relu) v = fmaxf(v, 0.f);
                if (outBf) ((__bf16*)Cp)[off] = (__bf16)v;
                else       ((float*)Cp)[off] = v;
            }
        }
    }
}

// =====================================================================
// ======  Fused flash attention (QK^T -> softmax -> PV), DH=192  ======
// =====================================================================
// qkv: [NB][T][3*CD] bf16 (Q at +0, K at +CD, V at +2CD, head h at +h*CDH)
// o:   [NB][T][CD]   bf16.  Grid: (T/128, NB*CH).  Block: 512 thr = 8 waves.
// Each wave owns a 16-row Q strip. S kept fp32 through online softmax.
__global__ __launch_bounds__(512) void flash_attn(
    const __bf16* __restrict__ qkv, __bf16* __restrict__ o, int T, float scl)
{
    int z = blockIdx.y;
    int b = z >> 1, h = z & 1;
    const __bf16* base = qkv + (long)b * T * 3 * CD + h * CDH;
    int qBase = blockIdx.x * 128;

    __shared__ __attribute__((aligned(16))) __bf16 Qs[128][200];
    __shared__ __attribute__((aligned(16))) __bf16 Ks[64][200];
    __shared__ __attribute__((aligned(16))) __bf16 Vt[192][72];
    __shared__ __attribute__((aligned(16))) __bf16 Ps[128][72];

    int tid  = threadIdx.x;
    int lane = tid & 63;
    int wave = tid >> 6;     // 0..7
    int quad = lane >> 4;
    int l16  = lane & 15;
    int wq   = wave * 16;    // Q-strip base row (within tile)

    // ---- stage Q tile (128 x 192): 3072 uint4 / 512 thr = 6 each
#pragma unroll
    for (int i = 0; i < 6; ++i) {
        int u = tid + i * 512;
        int r = u / 24, c = (u % 24) * 8;
        *(uint4*)(&Qs[r][c]) = *(const uint4*)(base + (long)(qBase + r) * 3 * CD + c);
    }

    f32x4 oacc[12];
#pragma unroll
    for (int j = 0; j < 12; ++j) oacc[j] = (f32x4){0.f, 0.f, 0.f, 0.f};
    float mrow[4], lrow[4];
#pragma unroll
    for (int r = 0; r < 4; ++r) { mrow[r] = -3.0e38f; lrow[r] = 0.f; }

    for (int kv0 = 0; kv0 < T; kv0 += 64) {
        __syncthreads();   // prev PV reads of Ks/Vt done
        // stage K (64 x 192): 1536 uint4 / 512 = 3 each
#pragma unroll
        for (int i = 0; i < 3; ++i) {
            int u = tid + i * 512;
            int r = u / 24, c = (u % 24) * 8;
            *(uint4*)(&Ks[r][c]) = *(const uint4*)(base + CD + (long)(kv0 + r) * 3 * CD + c);
        }
        // stage V transposed -> Vt[dh][kv]
#pragma unroll
        for (int i = 0; i < 3; ++i) {
            int u = tid + i * 512;
            int r = u / 24, c = (u % 24) * 8;
            uint4 pkt = *(const uint4*)(base + 2 * CD + (long)(kv0 + r) * 3 * CD + c);
            const __bf16* v8 = (const __bf16*)&pkt;
#pragma unroll
            for (int j = 0; j < 8; ++j) Vt[c + j][r] = v8[j];
        }
        __syncthreads();

        // ---- S = Q @ K^T  (wave strip: 16 rows x 64 cols), K=192
        f32x4 s[4];
#pragma unroll
        for (int nt = 0; nt < 4; ++nt) s[nt] = (f32x4){0.f, 0.f, 0.f, 0.f};
#pragma unroll
        for (int ks = 0; ks < 6; ++ks) {
            bf16x8 aq = *(const bf16x8*)(&Qs[wq + l16][ks * 32 + quad * 8]);
#pragma unroll
            for (int nt = 0; nt < 4; ++nt) {
                bf16x8 bk = *(const bf16x8*)(&Ks[nt * 16 + l16][ks * 32 + quad * 8]);
                s[nt] = __builtin_amdgcn_mfma_f32_16x16x32_bf16(aq, bk, s[nt], 0, 0, 0);
            }
        }
        // ---- online softmax (rows = wq + quad*4 + r, cols = nt*16 + l16)
        float alpha[4];
#pragma unroll
        for (int r = 0; r < 4; ++r) {
            float mx = -3.0e38f;
#pragma unroll
            for (int nt = 0; nt < 4; ++nt) {
                s[nt][r] *= scl;
                mx = fmaxf(mx, s[nt][r]);
            }
            mx = fmaxf(mx, __shfl_xor(mx, 1));
            mx = fmaxf(mx, __shfl_xor(mx, 2));
            mx = fmaxf(mx, __shfl_xor(mx, 4));
            mx = fmaxf(mx, __shfl_xor(mx, 8));
            float mnew = fmaxf(mrow[r], mx);
            alpha[r] = __expf(mrow[r] - mnew);
            mrow[r] = mnew;
            float rs = 0.f;
#pragma unroll
            for (int nt = 0; nt < 4; ++nt) {
                float e = __expf(s[nt][r] - mnew);
                s[nt][r] = e;
                rs += e;
            }
            rs += __shfl_xor(rs, 1);
            rs += __shfl_xor(rs, 2);
            rs += __shfl_xor(rs, 4);
            rs += __shfl_xor(rs, 8);
            lrow[r] = lrow[r] * alpha[r] + rs;
        }
        // ---- P -> LDS (A-layout source for PV); own strip only, no barrier
#pragma unroll
        for (int r = 0; r < 4; ++r)
#pragma unroll
            for (int nt = 0; nt < 4; ++nt)
                Ps[wq + quad * 4 + r][nt * 16 + l16] = (__bf16)s[nt][r];
        // ---- rescale O
#pragma unroll
        for (int j = 0; j < 12; ++j)
#pragma unroll
            for (int r = 0; r < 4; ++r) oacc[j][r] *= alpha[r];
        // ---- O += P @ V   (K-dim = 64 kv rows)
#pragma unroll
        for (int ks2 = 0; ks2 < 2; ++ks2) {
            bf16x8 ap = *(const bf16x8*)(&Ps[wq + l16][ks2 * 32 + quad * 8]);
#pragma unroll
            for (int nt = 0; nt < 12; ++nt) {
                bf16x8 bv = *(const bf16x8*)(&Vt[nt * 16 + l16][ks2 * 32 + quad * 8]);
                oacc[nt] = __builtin_amdgcn_mfma_f32_16x16x32_bf16(ap, bv, oacc[nt], 0, 0, 0);
            }
        }
    }

    // ---- epilogue: O[row][dh] / l  -> o[b][qBase+row][h*CDH + dh]
    __bf16* ob = o + ((long)b * T + qBase + wq + quad * 4) * CD + h * CDH + l16;
#pragma unroll
    for (int r = 0; r < 4; ++r) {
        float inv = 1.0f / lrow[r];
#pragma unroll
        for (int nt = 0; nt < 12; ++nt)
            ob[(long)r * CD + nt * 16] = (__bf16)(oacc[nt][r] * inv);
    }
}

// ---- LN (input already has residual added): out32 = LN(a)*g+be ; bf16 padded copy ----
__global__ __launch_bounds__(CD) void ln_res(const float* __restrict__ a,
    const float* __restrict__ g, const float* __restrict__ be,
    float* __restrict__ out32, __bf16* __restrict__ outbf, int Tlog2)
{
    long r = blockIdx.x;
    int d = threadIdx.x;
    float v = a[r * CD + d];
    float s1 = v, s2 = v * v;
#pragma unroll
    for (int off = 32; off > 0; off >>= 1) {
        s1 += __shfl_down(s1, off);
        s2 += __shfl_down(s2, off);
    }
    __shared__ float sh1[CD / 64], sh2[CD / 64];
    int wv = d >> 6, ln = d & 63;
    if (ln == 0) { sh1[wv] = s1; sh2[wv] = s2; }
    __syncthreads();
    if (d == 0) {
        float t1 = 0.f, t2 = 0.f;
        for (int i = 0; i < CD / 64; ++i) { t1 += sh1[i]; t2 += sh2[i]; }
        sh1[0] = t1; sh2[0] = t2;
    }
    __syncthreads();
    float mean = sh1[0] * (1.0f / CD);
    float var  = sh2[0] * (1.0f / CD) - mean * mean;
    float res = (v - mean) * rsqrtf(var + 1e-5f) * g[d] + be[d];
    out32[r * CD + d] = res;
    int T = 1 << Tlog2;
    long bb = r >> Tlog2; int t = (int)(r & (T - 1));
    outbf[(bb * (T + 2) + t + 1) * CD + d] = (__bf16)res;
}

// ---- fp32 chunk -> bf16 padded ----
__global__ __launch_bounds__(CD) void f32_to_padbf16(const float* __restrict__ in,
    __bf16* __restrict__ out, int Tlog2)
{
    long r = blockIdx.x;
    int d = threadIdx.x;
    int T = 1 << Tlog2;
    long b = r >> Tlog2; int t = (int)(r & (T - 1));
    out[(b * (T + 2) + t + 1) * CD + d] = (__bf16)in[r * CD + d];
}

// ---- zero the pad rows of a padded buffer [NB][T+2][C] ----
__global__ void zero_pads(__bf16* __restrict__ p, int Tp2, int C)
{
    int b = blockIdx.x >> 1;
    int which = blockIdx.x & 1;
    long row = (long)b * Tp2 + (which ? Tp2 - 1 : 0);
    for (int c = threadIdx.x; c < C; c += blockDim.x) p[row * C + c] = (__bf16)0.f;
}

// ---- transpose fp32 [R,C] -> bf16 [C,R] ----
__global__ __launch_bounds__(256) void tr_f32_bf16(const float* __restrict__ in,
    __bf16* __restrict__ out, int R, int C)
{
    __shared__ float t[32][33];
    int c0 = blockIdx.x * 32, r0 = blockIdx.y * 32;
    int tx = threadIdx.x & 31, ty = threadIdx.x >> 5;
#pragma unroll
    for (int i = 0; i < 4; ++i) {
        int rr = ty * 4 + i;
        int r = r0 + rr, c = c0 + tx;
        if (r < R && c < C) t[rr][tx] = in[(long)r * C + c];
    }
    __syncthreads();
#pragma unroll
    for (int i = 0; i < 4; ++i) {
        int cc = ty * 4 + i;
        int c = c0 + cc, r = r0 + tx;
        if (c < C && r < R) out[(long)c * R + r] = (__bf16)t[tx][cc];
    }
}

// ---- conv weight [O,Cc,3] -> bf16 [O, 3*Cc] with (kk,c) order ----
__global__ void convw_bf16(const float* __restrict__ w, __bf16* __restrict__ wt,
                           int O, int Cc)
{
    long total = (long)O * 3 * Cc;
    int KC = 3 * Cc;
    for (long i = (long)blockIdx.x * blockDim.x + threadIdx.x; i < total;
         i += (long)gridDim.x * blockDim.x) {
        int j = (int)(i % KC); long o = i / KC;
        int kk = j / Cc, c = j % Cc;
        wt[i] = (__bf16)w[(o * Cc + c) * 3 + kk];
    }
}

// ---- embed + positional encoding (fp32 out) ----
__global__ __launch_bounds__(CD) void embed_pe_kernel(const int* __restrict__ x,
    const float* __restrict__ emb, float* __restrict__ h)
{
    int bs = blockIdx.x;
    int d  = threadIdx.x;
    int s  = bs & (CS - 1);
    int tok = x[bs];
    int i = d >> 1;
    float ang = (float)s * powf(10000.0f, -2.0f * (float)i / (float)CD);
    float pe = (d & 1) ? cosf(ang) : sinf(ang);
    h[(size_t)bs * CD + d] = emb[(size_t)tok * CD + d] + pe;
}

// ---- length regulation ----
__global__ __launch_bounds__(CS) void lenreg_kernel(const int* __restrict__ y,
    int* __restrict__ idx, int* __restrict__ totals)
{
    __shared__ int ends[CS];
    int b = blockIdx.x, tid = threadIdx.x;
    if (tid == 0) {
        int acc = 0;
        for (int s = 0; s < CS; ++s) { acc += y[b * CS + s]; ends[s] = acc; }
    }
    __syncthreads();
    for (int t = tid; t < CLOUT; t += CS) idx[b * CLOUT + t] = CS - 1;
    if (tid == 0) totals[b] = ends[CS - 1];
    __syncthreads();
    int st = (tid == 0) ? 0 : ends[tid - 1];
    int en = ends[tid];
    for (int t = st; t < en; ++t) idx[b * CLOUT + t] = tid;
}

// ---- gather/expand, dual output (chunk fp32 + padded bf16) ----
__global__ __launch_bounds__(CD) void gather_dual(const float* __restrict__ hph,
    const int* __restrict__ idx, const int* __restrict__ tot,
    float* __restrict__ h32, __bf16* __restrict__ hbf, int chunkBase)
{
    int rl = blockIdx.x;
    int rg = chunkBase + rl;
    int b = rg >> 10, t = rg & (CLOUT - 1);
    int d = threadIdx.x;
    int src = idx[rg];
    float v = (t < tot[b]) ? hph[((long)b * CS + src) * CD + d] : 0.f;
    h32[(long)rl * CD + d] = v;
    long bl = rl >> 10; int tl = rl & (CLOUT - 1);
    hbf[(bl * (CLOUT + 2) + tl + 1) * CD + d] = (__bf16)v;
}

// =====================================================================
// ===============  OLD fp32 FALLBACK PATH (round-2, verified) =========
// =====================================================================

constexpr int TS = 64;
constexpr int KT = 16;

__global__ __launch_bounds__(256) void gemm_nn(
    const float* __restrict__ A, int lda, long sA1, long sA2,
    const float* __restrict__ W, int ldw, long sW1, long sW2,
    const float* __restrict__ bias,
    float* __restrict__ C, int ldc, long sC1, long sC2,
    int M, int N, int Kd, int zdiv, int relu, float scale)
{
    int z = blockIdx.z;
    int zb = z / zdiv, zh = z % zdiv;
    A += (long)zb * sA1 + (long)zh * sA2;
    W += (long)zb * sW1 + (long)zh * sW2;
    C += (long)zb * sC1 + (long)zh * sC2;
    __shared__ float As[TS][KT + 1];
    __shared__ float Ws[KT][TS];
    int tx = threadIdx.x, ty = threadIdx.y;
    int tid = ty * 16 + tx;
    int mBase = blockIdx.y * TS, nBase = blockIdx.x * TS;
    float acc[4][4] = {};
    for (int k0 = 0; k0 < Kd; k0 += KT) {
#pragma unroll
        for (int l = 0; l < 4; ++l) {
            int o = tid + l * 256;
            int kc = o & 15, mm = o >> 4;
            int gr = mBase + mm, gk = k0 + kc;
            As[mm][kc] = (gr < M && gk < Kd) ? A[(long)gr * lda + gk] : 0.f;
        }
#pragma unroll
        for (int l = 0; l < 4; ++l) {
            int o = tid + l * 256;
            int nn = o & 63, kc = o >> 6;
            int gk = k0 + kc, gc = nBase + nn;
            Ws[kc][nn] = (gk < Kd && gc < N) ? W[(long)gk * ldw + gc] : 0.f;
        }
        __syncthreads();
#pragma unroll
        for (int kc = 0; kc < KT; ++kc) {
            float a[4], bb[4];
#pragma unroll
            for (int i = 0; i < 4; ++i) a[i] = As[ty * 4 + i][kc];
#pragma unroll
            for (int j = 0; j < 4; ++j) bb[j] = Ws[kc][tx * 4 + j];
#pragma unroll
            for (int i = 0; i < 4; ++i)
#pragma unroll
                for (int j = 0; j < 4; ++j)
                    acc[i][j] = fmaf(a[i], bb[j], acc[i][j]);
        }
        __syncthreads();
    }
#pragma unroll
    for (int i = 0; i < 4; ++i) {
        int r = mBase + ty * 4 + i;
        if (r >= M) continue;
#pragma unroll
        for (int j = 0; j < 4; ++j) {
            int c = nBase + tx * 4 + j;
            if (c >= N) continue;
            float v = acc[i][j] * scale + (bias ? bias[c] : 0.f);
            if (relu) v = fmaxf(v, 0.f);
            C[(long)r * ldc + c] = v;
        }
    }
}

__global__ __launch_bounds__(256) void gemm_nt(
    const float* __restrict__ A, int lda, long sA1, long sA2,
    const float* __restrict__ Bm, int ldb, long sB1, long sB2,
    float* __restrict__ C, int ldc, long sC1, long sC2,
    int M, int N, int Kd, int zdiv, float scale)
{
    int z = blockIdx.z;
    int zb = z / zdiv, zh = z % zdiv;
    A  += (long)zb * sA1 + (long)zh * sA2;
    Bm += (long)zb * sB1 + (long)zh * sB2;
    C  += (long)zb * sC1 + (long)zh * sC2;
    __shared__ float As[TS][KT + 1];
    __shared__ float Bs[TS][KT + 1];
    int tx = threadIdx.x, ty = threadIdx.y;
    int tid = ty * 16 + tx;
    int mBase = blockIdx.y * TS, nBase = blockIdx.x * TS;
    float acc[4][4] = {};
    for (int k0 = 0; k0 < Kd; k0 += KT) {
#pragma unroll
        for (int l = 0; l < 4; ++l) {
            int o = tid + l * 256;
            int kc = o & 15, mm = o >> 4;
            int gr = mBase + mm, gk = k0 + kc;
            As[mm][kc] = (gr < M && gk < Kd) ? A[(long)gr * lda + gk] : 0.f;
        }
#pragma unroll
        for (int l = 0; l < 4; ++l) {
            int o = tid + l * 256;
            int kc = o & 15, nn = o >> 4;
            int gn = nBase + nn, gk = k0 + kc;
            Bs[nn][kc] = (gn < N && gk < Kd) ? Bm[(long)gn * ldb + gk] : 0.f;
        }
        __syncthreads();
#pragma unroll
        for (int kc = 0; kc < KT; ++kc) {
            float a[4], bb[4];
#pragma unroll
            for (int i = 0; i < 4; ++i) a[i] = As[ty * 4 + i][kc];
#pragma unroll
            for (int j = 0; j < 4; ++j) bb[j] = Bs[tx * 4 + j][kc];
#pragma unroll
            for (int i = 0; i < 4; ++i)
#pragma unroll
                for (int j = 0; j < 4; ++j)
                    acc[i][j] = fmaf(a[i], bb[j], acc[i][j]);
        }
        __syncthreads();
    }
#pragma unroll
    for (int i = 0; i < 4; ++i) {
        int r = mBase + ty * 4 + i;
        if (r >= M) continue;
#pragma unroll
        for (int j = 0; j < 4; ++j) {
            int c = nBase + tx * 4 + j;
            if (c >= N) continue;
            C[(long)r * ldc + c] = acc[i][j] * scale;
        }
    }
}

__global__ __launch_bounds__(256) void conv_k3(
    const float* __restrict__ A, const float* __restrict__ Wt,
    const float* __restrict__ bias, float* __restrict__ Cout,
    int T, int tshift, int Cc, int O, int M, int relu)
{
    __shared__ float As[3][TS][KT + 1];
    __shared__ float Ws[3][KT][TS];
    int tx = threadIdx.x, ty = threadIdx.y;
    int tid = ty * 16 + tx;
    int mBase = blockIdx.y * TS, nBase = blockIdx.x * TS;
    float acc[4][4] = {};
    for (int k0 = 0; k0 < Cc; k0 += KT) {
#pragma unroll
        for (int kk = 0; kk < 3; ++kk) {
#pragma unroll
            for (int l = 0; l < 4; ++l) {
                int o = tid + l * 256;
                int kc = o & 15, mm = o >> 4;
                int gr = mBase + mm;
                int b = gr >> tshift, t = gr & (T - 1);
                int ts = t + kk - 1;
                float v = 0.f;
                if (gr < M && ts >= 0 && ts < T)
                    v = A[((long)(b << tshift) + ts) * Cc + k0 + kc];
                As[kk][mm][kc] = v;
            }
#pragma unroll
            for (int l = 0; l < 4; ++l) {
                int o = tid + l * 256;
                int nn = o & 63, kc = o >> 6;
                int gc = nBase + nn;
                Ws[kk][kc][nn] = (gc < O) ? Wt[((long)kk * Cc + k0 + kc) * O + gc] : 0.f;
            }
        }
        __syncthreads();
#pragma unroll
        for (int kk = 0; kk < 3; ++kk) {
#pragma unroll
            for (int kc = 0; kc < KT; ++kc) {
                float a[4], bb[4];
#pragma unroll
                for (int i = 0; i < 4; ++i) a[i] = As[kk][ty * 4 + i][kc];
#pragma unroll
                for (int j = 0; j < 4; ++j) bb[j] = Ws[kk][kc][tx * 4 + j];
#pragma unroll
                for (int i = 0; i < 4; ++i)
#pragma unroll
                    for (int j = 0; j < 4; ++j)
                        acc[i][j] = fmaf(a[i], bb[j], acc[i][j]);
            }
        }
        __syncthreads();
    }
#pragma unroll
    for (int i = 0; i < 4; ++i) {
        int r = mBase + ty * 4 + i;
        if (r >= M) continue;
#pragma unroll
        for (int j = 0; j < 4; ++j) {
            int c = nBase + tx * 4 + j;
            if (c >= O) continue;
            float v = acc[i][j] + bias[c];
            if (relu) v = fmaxf(v, 0.f);
            Cout[(long)r * O + c] = v;
        }
    }
}

__global__ void transpose_w(const float* __restrict__ W, float* __restrict__ Wt,
                            int Cc, int O)
{
    int total = 3 * Cc * O;
    for (int i = blockIdx.x * blockDim.x + threadIdx.x; i < total;
         i += gridDim.x * blockDim.x) {
        int o = i % O; int rest = i / O; int c = rest % Cc; int kk = rest / Cc;
        Wt[i] = W[((long)o * Cc + c) * 3 + kk];
    }
}

__global__ __launch_bounds__(CD) void ln_kernel(const float* __restrict__ a,
    const float* __restrict__ bsrc, const float* __restrict__ g,
    const float* __restrict__ be, float* __restrict__ out)
{
    long r = blockIdx.x;
    int d = threadIdx.x;
    float v = a[r * CD + d] + bsrc[r * CD + d];
    float s1 = v, s2 = v * v;
#pragma unroll
    for (int off = 32; off > 0; off >>= 1) {
        s1 += __shfl_down(s1, off);
        s2 += __shfl_down(s2, off);
    }
    __shared__ float sh1[CD / 64], sh2[CD / 64];
    int wv = d >> 6, ln = d & 63;
    if (ln == 0) { sh1[wv] = s1; sh2[wv] = s2; }
    __syncthreads();
    if (d == 0) {
        float t1 = 0.f, t2 = 0.f;
        for (int i = 0; i < CD / 64; ++i) { t1 += sh1[i]; t2 += sh2[i]; }
        sh1[0] = t1; sh2[0] = t2;
    }
    __syncthreads();
    float mean = sh1[0] * (1.0f / CD);
    float var  = sh2[0] * (1.0f / CD) - mean * mean;
    out[r * CD + d] = (v - mean) * rsqrtf(var + 1e-5f) * g[d] + be[d];
}

__global__ __launch_bounds__(256) void softmax_rows(float* __restrict__ sc, int T)
{
    long r = blockIdx.x;
    float* row = sc + r * (long)T;
    int tid = threadIdx.x;
    float mx = -3.4e38f;
    for (int i = tid; i < T; i += 256) mx = fmaxf(mx, row[i]);
#pragma unroll
    for (int off = 32; off > 0; off >>= 1) mx = fmaxf(mx, __shfl_down(mx, off));
    __shared__ float sh[4];
    int wv = tid >> 6, ln = tid & 63;
    if (ln == 0) sh[wv] = mx;
    __syncthreads();
    if (tid == 0) { float m = sh[0]; for (int i = 1; i < 4; ++i) m = fmaxf(m, sh[i]); sh[0] = m; }
    __syncthreads();
    mx = sh[0];
    __syncthreads();
    float sum = 0.f;
    for (int i = tid; i < T; i += 256) {
        float e = __expf(row[i] - mx);
        row[i] = e;
        sum += e;
    }
#pragma unroll
    for (int off = 32; off > 0; off >>= 1) sum += __shfl_down(sum, off);
    if (ln == 0) sh[wv] = sum;
    __syncthreads();
    if (tid == 0) { float s = 0.f; for (int i = 0; i < 4; ++i) s += sh[i]; sh[0] = s; }
    __syncthreads();
    float inv = 1.0f / sh[0];
    for (int i = tid; i < T; i += 256) row[i] *= inv;
}

__global__ __launch_bounds__(CD) void gather_expand(const float* __restrict__ h,
    const int* __restrict__ idx, const int* __restrict__ totals,
    float* __restrict__ out)
{
    int r = blockIdx.x;
    int b = r >> 10, t = r & (CLOUT - 1);
    int d = threadIdx.x;
    int src = idx[r];
    float v = (t < totals[b]) ? h[((long)b * CS + src) * CD + d] : 0.f;
    out[(long)r * CD + d] = v;
}

static inline void launch_nn(hipStream_t st,
    const float* A, int lda, long sA1, long sA2,
    const float* W, int ldw, long sW1, long sW2, const float* bias,
    float* C, int ldc, long sC1, long sC2,
    int M, int N, int Kd, int nz, int zdiv, int relu, float scale)
{
    dim3 g((N + TS - 1) / TS, (M + TS - 1) / TS, nz), b(16, 16, 1);
    hipLaunchKernelGGL(gemm_nn, g, b, 0, st, A, lda, sA1, sA2, W, ldw, sW1, sW2,
                       bias, C, ldc, sC1, sC2, M, N, Kd, zdiv, relu, scale);
}

static inline void launch_nt(hipStream_t st,
    const float* A, int lda, long sA1, long sA2,
    const float* Bm, int ldb, long sB1, long sB2,
    float* C, int ldc, long sC1, long sC2,
    int M, int N, int Kd, int nz, int zdiv, float scale)
{
    dim3 g((N + TS - 1) / TS, (M + TS - 1) / TS, nz), b(16, 16, 1);
    hipLaunchKernelGGL(gemm_nt, g, b, 0, st, A, lda, sA1, sA2, Bm, ldb, sB1, sB2,
                       C, ldc, sC1, sC2, M, N, Kd, zdiv, scale);
}

static void fft_chunk_f32(hipStream_t st, float* hch, int NBc, int T, int tshift,
    float* x_c, float* qkv_c, float* o_c, float* t_c, float* s_c,
    const float* wt1, const float* wt2,
    const float* qkv_w, const float* qkv_b, const float* out_w, const float* out_b,
    const float* g1, const float* b1, const float* c1b, const float* c2b,
    const float* g2, const float* b2)
{
    const int M = NBc * T;
    const float scl = 1.0f / sqrtf((float)CDH);
    launch_nn(st, hch, CD, 0, 0, qkv_w, 3 * CD, 0, 0, qkv_b,
              qkv_c, 3 * CD, 0, 0, M, 3 * CD, CD, 1, 1, 0, 1.f);
    launch_nt(st, qkv_c, 3 * CD, (long)T * 3 * CD, CDH,
              qkv_c + CD, 3 * CD, (long)T * 3 * CD, CDH,
              s_c, T, (long)CH * T * T, (long)T * T,
              T, T, CDH, NBc * CH, CH, scl);
    hipLaunchKernelGGL(softmax_rows, dim3(NBc * CH * T), dim3(256), 0, st, s_c, T);
    launch_nn(st, s_c, T, (long)CH * T * T, (long)T * T,
              qkv_c + 2 * CD, 3 * CD, (long)T * 3 * CD, CDH, nullptr,
              o_c, CD, (long)T * CD, CDH,
              T, CDH, T, NBc * CH, CH, 0, 1.f);
    launch_nn(st, o_c, CD, 0, 0, out_w, CD, 0, 0, out_b,
              t_c, CD, 0, 0, M, CD, CD, 1, 1, 0, 1.f);
    hipLaunchKernelGGL(ln_kernel, dim3(M), dim3(CD), 0, st, t_c, hch, g1, b1, x_c);
    hipLaunchKernelGGL(conv_k3, dim3(CDF / TS, M / TS), dim3(16, 16), 0, st,
                       x_c, wt1, c1b, s_c, T, tshift, CD, CDF, M, 1);
    hipLaunchKernelGGL(conv_k3, dim3(CD / TS, M / TS), dim3(16, 16), 0, st,
                       s_c, wt2, c2b, t_c, T, tshift, CDF, CD, M, 0);
    hipLaunchKernelGGL(ln_kernel, dim3(M), dim3(CD), 0, st, t_c, x_c, g2, b2, hch);
}

static void run_fp32_path(void* const* d_in, int n_in, void* d_out, void* d_ws,
                          size_t ws_size, hipStream_t stream)
{
    const int* x = (const int*)d_in[0];
    const int* y = (const int*)d_in[1];
    const float* P[40];
    for (int i = 0; i < n_in && i < 40; ++i) P[i] = (const float*)d_in[i];

    constexpr long E_HMEL = (long)CB * CLOUT * CD;
    constexpr long E_HPH  = (long)CB * CS * CD;
    constexpr long E_WT   = 3L * CD * CDF;
    constexpr long E_IDX  = (long)CB * CLOUT + CB;
    constexpr long E_PB   = 4456448L;
    const long fixedElems = E_HMEL + E_HPH + 2 * E_WT + E_IDX;

    int NB = 1;
    for (int cand = 16; cand >= 1; cand >>= 1) {
        long tot = fixedElems + (long)cand * E_PB;
        if ((size_t)tot * sizeof(float) <= ws_size) { NB = cand; break; }
    }

    float* ws   = (float*)d_ws;
    long off = 0;
    float* hMel = ws + off; off += E_HMEL;
    float* hPh  = ws + off; off += E_HPH;
    float* wt1  = ws + off; off += E_WT;
    float* wt2  = ws + off; off += E_WT;
    int*   idxb = (int*)(ws + off); off += E_IDX;
    int*   totb = idxb + (long)CB * CLOUT;
    float* xc   = ws + off; off += (long)NB * CLOUT * CD;
    float* qkvc = ws + off; off += (long)NB * CLOUT * 3 * CD;
    float* oc   = ws + off; off += (long)NB * CLOUT * CD;
    float* tc   = ws + off; off += (long)NB * CLOUT * CD;
    float* sc   = ws + off;

    hipLaunchKernelGGL(embed_pe_kernel, dim3(CB * CS), dim3(CD), 0, stream, x, P[2], hPh);
    for (int l = 0; l < CL; ++l) {
        hipLaunchKernelGGL(transpose_w, dim3(256), dim3(256), 0, stream,
                           P[9]  + (long)l * CDF * CD * 3, wt1, CD, CDF);
        hipLaunchKernelGGL(transpose_w, dim3(256), dim3(256), 0, stream,
                           P[11] + (long)l * CD * CDF * 3, wt2, CDF, CD);
        for (int c = 0; c < CB / NB; ++c)
            fft_chunk_f32(stream, hPh + (long)c * NB * CS * CD, NB, CS, 7,
                          xc, qkvc, oc, tc, sc, wt1, wt2,
                          P[3] + (long)l * CD * 3 * CD, P[4] + (long)l * 3 * CD,
                          P[5] + (long)l * CD * CD, P[6] + (long)l * CD,
                          P[7] + (long)l * CD, P[8] + (long)l * CD,
                          P[10] + (long)l * CDF, P[12] + (long)l * CD,
                          P[13] + (long)l * CD, P[14] + (long)l * CD);
    }
    hipLaunchKernelGGL(lenreg_kernel, dim3(CB), dim3(CS), 0, stream, y, idxb, totb);
    hipLaunchKernelGGL(gather_expand, dim3(CB * CLOUT), dim3(CD), 0, stream,
                       hPh, idxb, totb, hMel);
    for (int l = 0; l < CL; ++l) {
        hipLaunchKernelGGL(transpose_w, dim3(256), dim3(256), 0, stream,
                           P[21] + (long)l * CDF * CD * 3, wt1, CD, CDF);
        hipLaunchKernelGGL(transpose_w, dim3(256), dim3(256), 0, stream,
                           P[23] + (long)l * CD * CDF * 3, wt2, CDF, CD);
        for (int c = 0; c < CB / NB; ++c)
            fft_chunk_f32(stream, hMel + (long)c * NB * CLOUT * CD, NB, CLOUT, 10,
                          xc, qkvc, oc, tc, sc, wt1, wt2,
                          P[15] + (long)l * CD * 3 * CD, P[16] + (long)l * 3 * CD,
                          P[17] + (long)l * CD * CD, P[18] + (long)l * CD,
                          P[19] + (long)l * CD, P[20] + (long)l * CD,
                          P[22] + (long)l * CDF, P[24] + (long)l * CD,
                          P[25] + (long)l * CD, P[26] + (long)l * CD);
    }
    launch_nn(stream, hMel, CD, 0, 0, P[37], CNM, 0, 0, P[38],
              (float*)d_out, CNM, 0, 0, CB * CLOUT, CNM, CD, 1, 1, 0, 1.f);
}

// =====================================================================
// ===============  bf16 path driver  ==================================
// =====================================================================

static inline void mm(hipStream_t st, const __bf16* A, long lda, long sA1, long sA2,
    const __bf16* Bt, long ldb, long sB1, long sB2, const float* bias,
    const float* resid, void* C, long ldc, long sC1, long sC2, int M, int N, int K,
    int nz, int zdiv, int relu, int outBf, float scale)
{
    dim3 g((N + 127) / 128, M / 128, nz), b(256, 1, 1);
    hipLaunchKernelGGL(mm_bf16, g, b, 0, st, A, lda, sA1, sA2, Bt, ldb, sB1, sB2,
                       bias, resid, C, ldc, sC1, sC2, M, N, K, zdiv, relu, outBf, scale);
}

struct Scr {
    float *h32, *x32, *tmp32;
    __bf16 *hbf, *xbf, *qkv, *c1p, *o;
};

static size_t scr_layout(char* base, int NB, int T, Scr* s)
{
    auto align = [](size_t v) { return (v + 255) & ~(size_t)255; };
    size_t off = 0;
    long Tp2 = T + 2;
    if (s) s->h32 = (float*)(base + off);
    off = align(off + (size_t)NB * T * CD * 4);
    if (s) s->x32 = (float*)(base + off);
    off = align(off + (size_t)NB * T * CD * 4);
    if (s) s->tmp32 = (float*)(base + off);
    off = align(off + (size_t)NB * T * CD * 4);
    if (s) s->hbf = (__bf16*)(base + off);
    off = align(off + (size_t)NB * Tp2 * CD * 2);
    if (s) s->xbf = (__bf16*)(base + off);
    off = align(off + (size_t)NB * Tp2 * CD * 2);
    if (s) s->qkv = (__bf16*)(base + off);
    off = align(off + (size_t)NB * T * 3 * CD * 2);
    if (s) s->c1p = (__bf16*)(base + off);
    off = align(off + (size_t)NB * Tp2 * CDF * 2);
    if (s) s->o = (__bf16*)(base + off);
    off = align(off + (size_t)NB * T * CD * 2);
    return off;
}

// per-layer bf16 weight offsets (elements)
constexpr long W_QKV = 0;
constexpr long W_OUT = 442368;       // 1152*384
constexpr long W_C1  = 589824;       // + 384*384
constexpr long W_C2  = 2359296;      // + 1536*1152
constexpr long WLAYER = 4128768;     // + 384*4608
constexpr long WSTACK = 6 * WLAYER;
constexpr long WTOT   = WSTACK + 30720;  // + proj 80*384

static void convert_stack_weights(hipStream_t st, __bf16* wbuf,
    const float* qkv_w, const float* out_w, const float* c1w, const float* c2w)
{
    for (int l = 0; l < CL; ++l) {
        __bf16* wl = wbuf + (long)l * WLAYER;
        hipLaunchKernelGGL(tr_f32_bf16, dim3(36, 12), dim3(256), 0, st,
                           qkv_w + (long)l * CD * 3 * CD, wl + W_QKV, CD, 3 * CD);
        hipLaunchKernelGGL(tr_f32_bf16, dim3(12, 12), dim3(256), 0, st,
                           out_w + (long)l * CD * CD, wl + W_OUT, CD, CD);
        hipLaunchKernelGGL(convw_bf16, dim3(2048), dim3(256), 0, st,
                           c1w + (long)l * CDF * CD * 3, wl + W_C1, CDF, CD);
        hipLaunchKernelGGL(convw_bf16, dim3(2048), dim3(256), 0, st,
                           c2w + (long)l * CD * CDF * 3, wl + W_C2, CD, CDF);
    }
}

static void fft_block_bf16(hipStream_t st, const Scr& S, int NBc, int T, int tlog2,
    float* h32, const __bf16* wl,
    const float* qkv_b, const float* out_b,
    const float* g1, const float* b1, const float* c1b, const float* c2b,
    const float* g2, const float* b2)
{
    const int M = NBc * T;
    const long Tp2 = T + 2;
    const float scl = 1.0f / sqrtf((float)CDH);

    // qkv = h @ Wqkv + b   (A = padded h_bf, z over batches)
    mm(st, S.hbf + CD, CD, Tp2 * CD, 0, wl + W_QKV, CD, 0, 0, qkv_b, nullptr,
       S.qkv, 3 * CD, (long)T * 3 * CD, 0, T, 3 * CD, CD, NBc, 1, 0, 1, 1.f);

    // fused attention: QK^T -> online softmax -> PV  (o bf16)
    hipLaunchKernelGGL(flash_attn, dim3(T / 128, NBc * CH), dim3(512), 0, st,
                       S.qkv, S.o, T, scl);

    // tmp = o @ Wout + b + h (residual fused)
    mm(st, S.o, CD, 0, 0, wl + W_OUT, CD, 0, 0, out_b, h32,
       S.tmp32, CD, 0, 0, M, CD, CD, 1, 1, 0, 0, 1.f);

    // x = LN(tmp) -> x32 + xbf(padded)
    hipLaunchKernelGGL(ln_res, dim3(M), dim3(CD), 0, st,
                       S.tmp32, g1, b1, S.x32, S.xbf, tlog2);

    // conv1: relu(x * W1) -> c1p rows 1..T (bf16)
    mm(st, S.xbf, CD, Tp2 * CD, 0, wl + W_C1, 3 * CD, 0, 0, c1b, nullptr,
       (void*)(S.c1p + CDF), CDF, Tp2 * CDF, 0,
       T, CDF, 3 * CD, NBc, 1, 1, 1, 1.f);

    // tmp = conv2 + x (residual fused)
    mm(st, S.c1p, CDF, Tp2 * CDF, 0, wl + W_C2, 3 * CDF, 0, 0, c2b, S.x32,
       S.tmp32, CD, (long)T * CD, 0,
       T, CD, 3 * CDF, NBc, 1, 0, 0, 1.f);

    // h = LN(tmp) -> h32 + hbf(padded)
    hipLaunchKernelGGL(ln_res, dim3(M), dim3(CD), 0, st,
                       S.tmp32, g2, b2, h32, S.hbf, tlog2);
}

extern "C" void kernel_launch(void* const* d_in, const int* in_sizes, int n_in,
                              void* d_out, int out_size, void* d_ws, size_t ws_size,
                              hipStream_t stream)
{
    (void)in_sizes; (void)out_size;

    const int* x = (const int*)d_in[0];
    const int* y = (const int*)d_in[1];
    const float* P[40];
    for (int i = 0; i < n_in && i < 40; ++i) P[i] = (const float*)d_in[i];

    // fixed region: bf16 weights + hPh fp32 + idx
    size_t wbufB  = ((size_t)WTOT * 2 + 255) & ~(size_t)255;
    size_t hphB   = ((size_t)CB * CS * CD * 4 + 255) & ~(size_t)255;
    size_t idxB   = (((size_t)CB * CLOUT + CB) * 4 + 255) & ~(size_t)255;
    size_t fixedB = wbufB + hphB + idxB;

    size_t scrB = (ws_size > fixedB) ? (ws_size - fixedB) : 0;

    int NBmel = 0;
    for (int cand = 16; cand >= 1; cand >>= 1)
        if (scr_layout(nullptr, cand, CLOUT, nullptr) <= scrB) { NBmel = cand; break; }
    if (NBmel == 0) { run_fp32_path(d_in, n_in, d_out, d_ws, ws_size, stream); return; }

    int NBph = 1;
    for (int cand = 16; cand >= 1; cand >>= 1)
        if (scr_layout(nullptr, cand, CS, nullptr) <= scrB) { NBph = cand; break; }

    char* base = (char*)d_ws;
    __bf16* wbuf = (__bf16*)base;
    float*  hPh  = (float*)(base + wbufB);
    int*    idxb = (int*)(base + wbufB + hphB);
    int*    totb = idxb + (long)CB * CLOUT;
    char*   scrbase = base + fixedB;

    // ================= phoneme encoder =================
    convert_stack_weights(stream, wbuf, P[3], P[5], P[9], P[11]);

    Scr Sp; scr_layout(scrbase, NBph, CS, &Sp);
    hipLaunchKernelGGL(zero_pads, dim3(NBph * 2), dim3(256), 0, stream, Sp.hbf, CS + 2, CD);
    hipLaunchKernelGGL(zero_pads, dim3(NBph * 2), dim3(256), 0, stream, Sp.xbf, CS + 2, CD);
    hipLaunchKernelGGL(zero_pads, dim3(NBph * 2), dim3(256), 0, stream, Sp.c1p, CS + 2, CDF);

    hipLaunchKernelGGL(embed_pe_kernel, dim3(CB * CS), dim3(CD), 0, stream, x, P[2], hPh);

    for (int c = 0; c < CB / NBph; ++c) {
        float* hch = hPh + (long)c * NBph * CS * CD;
        hipLaunchKernelGGL(f32_to_padbf16, dim3(NBph * CS), dim3(CD), 0, stream,
                           hch, Sp.hbf, 7);
        for (int l = 0; l < CL; ++l)
            fft_block_bf16(stream, Sp, NBph, CS, 7, hch, wbuf + (long)l * WLAYER,
                           P[4] + (long)l * 3 * CD, P[6] + (long)l * CD,
                           P[7] + (long)l * CD, P[8] + (long)l * CD,
                           P[10] + (long)l * CDF, P[12] + (long)l * CD,
                           P[13] + (long)l * CD, P[14] + (long)l * CD);
    }

    // ================= length regulation =================
    hipLaunchKernelGGL(lenreg_kernel, dim3(CB), dim3(CS), 0, stream, y, idxb, totb);

    // ================= mel decoder =================
    convert_stack_weights(stream, wbuf, P[15], P[17], P[21], P[23]);
    hipLaunchKernelGGL(tr_f32_bf16, dim3(3, 12), dim3(256), 0, stream,
                       P[37], wbuf + WSTACK, CD, CNM);

    Scr Sm; scr_layout(scrbase, NBmel, CLOUT, &Sm);
    hipLaunchKernelGGL(zero_pads, dim3(NBmel * 2), dim3(256), 0, stream, Sm.hbf, CLOUT + 2, CD);
    hipLaunchKernelGGL(zero_pads, dim3(NBmel * 2), dim3(256), 0, stream, Sm.xbf, CLOUT + 2, CD);
    hipLaunchKernelGGL(zero_pads, dim3(NBmel * 2), dim3(256), 0, stream, Sm.c1p, CLOUT + 2, CDF);

    for (int c = 0; c < CB / NBmel; ++c) {
        hipLaunchKernelGGL(gather_dual, dim3(NBmel * CLOUT), dim3(CD), 0, stream,
                           hPh, idxb, totb, Sm.h32, Sm.hbf, c * NBmel * CLOUT);
        for (int l = 0; l < CL; ++l)
            fft_block_bf16(stream, Sm, NBmel, CLOUT, 10, Sm.h32, wbuf + (long)l * WLAYER,
                           P[16] + (long)l * 3 * CD, P[18] + (long)l * CD,
                           P[19] + (long)l * CD, P[20] + (long)l * CD,
                           P[22] + (long)l * CDF, P[24] + (long)l * CD,
                           P[25] + (long)l * CD, P[26] + (long)l * CD);
        // final projection for this chunk (A = padded h_bf from last LN)
        mm(stream, Sm.hbf + CD, CD, (long)(CLOUT + 2) * CD, 0,
           wbuf + WSTACK, CD, 0, 0, P[38], nullptr,
           (float*)d_out + (long)c * NBmel * CLOUT * CNM, CNM, (long)CLOUT * CNM, 0,
           CLOUT, CNM, CD, NBmel, 1, 0, 0, 1.f);
    }
}

// Round 8
// 3976.910 us; speedup vs baseline: 1.5315x; 1.1184x over previous
//
#include <hip/hip_runtime.h>
#include <cstddef>
#include <cmath>

// ---------------- problem constants ----------------
constexpr int CB  = 16;
constexpr int CS  = 128;
constexpr int CD  = 384;
constexpr int CDF = 1536;
constexpr int CH  = 2;
constexpr int CL  = 6;
constexpr int CNM = 80;
constexpr int CLOUT = 1024;
constexpr int CDH = 192;

typedef __bf16 bf16x8 __attribute__((ext_vector_type(8)));
typedef float  f32x4  __attribute__((ext_vector_type(4)));

// =====================================================================
// ======  bf16 MFMA GEMM (verified padded-LDS staging)  ===============
// =====================================================================
constexpr int LDT = 72;
__global__ __launch_bounds__(256) void mm_bf16(
    const __bf16* __restrict__ A, long lda, long sA1, long sA2,
    const __bf16* __restrict__ Bt, long ldb, long sB1, long sB2,
    const float* __restrict__ bias, const float* __restrict__ resid,
    void* __restrict__ Cp, long ldc, long sC1, long sC2,
    int M, int N, int K, int zdiv, int relu, int outBf, float scale)
{
    int z = blockIdx.z;
    int zb = z / zdiv, zh = z % zdiv;
    const __bf16* Ab = A  + (long)zb * sA1 + (long)zh * sA2;
    const __bf16* Bb = Bt + (long)zb * sB1 + (long)zh * sB2;
    long coff = (long)zb * sC1 + (long)zh * sC2;

    __shared__ __attribute__((aligned(16))) __bf16 As[128 * LDT];
    __shared__ __attribute__((aligned(16))) __bf16 Bs[128 * LDT];

    int tid  = threadIdx.x;
    int lane = tid & 63;
    int wave = tid >> 6;
    int quad = lane >> 4;
    int l16  = lane & 15;
    int wm = (wave >> 1) * 64;
    int wn = (wave & 1) * 64;

    int mBase = blockIdx.y * 128;
    int nBase = blockIdx.x * 128;

    int trow  = tid >> 3;
    int tcol8 = (tid & 7) * 8;

    f32x4 acc[4][4] = {};

    for (int k0 = 0; k0 < K; k0 += 64) {
#pragma unroll
        for (int p = 0; p < 4; ++p) {
            int r = p * 32 + trow;
            const __bf16* ga = Ab + (long)(mBase + r) * lda + k0 + tcol8;
            *(uint4*)(&As[r * LDT + tcol8]) = *(const uint4*)ga;
            int gn = nBase + r; gn = gn < N ? gn : N - 1;
            const __bf16* gb = Bb + (long)gn * ldb + k0 + tcol8;
            *(uint4*)(&Bs[r * LDT + tcol8]) = *(const uint4*)gb;
        }
        __syncthreads();
#pragma unroll
        for (int ks = 0; ks < 2; ++ks) {
            int kof = ks * 32 + quad * 8;
            bf16x8 af[4], bfr[4];
#pragma unroll
            for (int mt = 0; mt < 4; ++mt)
                af[mt] = *(const bf16x8*)(&As[(wm + mt * 16 + l16) * LDT + kof]);
#pragma unroll
            for (int nt = 0; nt < 4; ++nt)
                bfr[nt] = *(const bf16x8*)(&Bs[(wn + nt * 16 + l16) * LDT + kof]);
#pragma unroll
            for (int mt = 0; mt < 4; ++mt)
#pragma unroll
                for (int nt = 0; nt < 4; ++nt)
                    acc[mt][nt] = __builtin_amdgcn_mfma_f32_16x16x32_bf16(
                        af[mt], bfr[nt], acc[mt][nt], 0, 0, 0);
        }
        __syncthreads();
    }

#pragma unroll
    for (int mt = 0; mt < 4; ++mt) {
#pragma unroll
        for (int nt = 0; nt < 4; ++nt) {
            int col = nBase + wn + nt * 16 + l16;
            if (col >= N) continue;
            int row0 = mBase + wm + mt * 16 + quad * 4;
            float bv = bias ? bias[col] : 0.f;
#pragma unroll
            for (int r = 0; r < 4; ++r) {
                long off = coff + (long)(row0 + r) * ldc + col;
                float v = acc[mt][nt][r] * scale + bv;
                if (resid) v += resid[off];
                if (relu) v = fmaxf(v, 0.f);
                if (outBf) ((__bf16*)Cp)[off] = (__bf16)v;
                else       ((float*)Cp)[off] = v;
            }
        }
    }
}

// =====================================================================
// ======  Windowed K=3 conv as MFMA GEMM (A rows staged ONCE)  ========
// =====================================================================
// Apad: [NB][Tp2][Cc] bf16, zero pad rows at 0 and Tp2-1 (data t at row 1+t).
// W: [O][3*Cc] bf16, (kk,c) order.  out[z][t][o] = sum_{kk,c} Apad[z][t+kk][c]*W[o][kk*Cc+c].
// Grid (O/128, T/128, NB), 512 thr = 8 waves, wave tile 32x64.
// LDS: A window 130 rows x 64 (staged once per c-chunk), B: 3 tap-tiles 128x64.
__global__ __launch_bounds__(512) void conv_mfma(
    const __bf16* __restrict__ Apad, const __bf16* __restrict__ W,
    const float* __restrict__ bias, const float* __restrict__ resid,
    void* __restrict__ Cp, long ldc, long sC1,
    int T, int Tp2, int Cc, int O, int relu, int outBf)
{
    int z = blockIdx.z;
    int t0 = blockIdx.y * 128;
    int nBase = blockIdx.x * 128;
    const __bf16* Ab = Apad + ((long)z * Tp2 + t0) * Cc;   // LDS row r <-> pad row t0+r

    __shared__ __attribute__((aligned(16))) __bf16 As[130 * LDT];
    __shared__ __attribute__((aligned(16))) __bf16 Bs[3][128 * LDT];

    int tid  = threadIdx.x;
    int lane = tid & 63;
    int wave = tid >> 6;         // 0..7
    int quad = lane >> 4;
    int l16  = lane & 15;
    int wm = (wave >> 1) * 32;   // 0,32,64,96
    int wn = (wave & 1) * 64;    // 0,64

    f32x4 acc[2][4] = {};

    long ldw = 3L * Cc;
    for (int c0 = 0; c0 < Cc; c0 += 64) {
        __syncthreads();
        // stage A: 130 rows x 64 cols (1040 uint4 over 512 thr)
#pragma unroll
        for (int i = 0; i < 3; ++i) {
            int u = tid + i * 512;
            if (u < 1040) {
                int r = u >> 3, cc = (u & 7) * 8;
                *(uint4*)(&As[r * LDT + cc]) = *(const uint4*)(Ab + (long)r * Cc + c0 + cc);
            }
        }
        // stage B: 3 taps x 128 rows x 64 cols (3072 uint4 = 6/thr)
#pragma unroll
        for (int i = 0; i < 6; ++i) {
            int u = tid + i * 512;
            int kk = u >> 10, rr = (u >> 3) & 127, cc = (u & 7) * 8;
            *(uint4*)(&Bs[kk][rr * LDT + cc]) =
                *(const uint4*)(W + (long)(nBase + rr) * ldw + kk * Cc + c0 + cc);
        }
        __syncthreads();
#pragma unroll
        for (int kk = 0; kk < 3; ++kk) {
#pragma unroll
            for (int ks = 0; ks < 2; ++ks) {
                int kof = ks * 32 + quad * 8;
                bf16x8 a0 = *(const bf16x8*)(&As[(wm + l16 + kk) * LDT + kof]);
                bf16x8 a1 = *(const bf16x8*)(&As[(wm + 16 + l16 + kk) * LDT + kof]);
                bf16x8 b0 = *(const bf16x8*)(&Bs[kk][(wn + l16) * LDT + kof]);
                bf16x8 b1 = *(const bf16x8*)(&Bs[kk][(wn + 16 + l16) * LDT + kof]);
                bf16x8 b2 = *(const bf16x8*)(&Bs[kk][(wn + 32 + l16) * LDT + kof]);
                bf16x8 b3 = *(const bf16x8*)(&Bs[kk][(wn + 48 + l16) * LDT + kof]);
                acc[0][0] = __builtin_amdgcn_mfma_f32_16x16x32_bf16(a0, b0, acc[0][0], 0, 0, 0);
                acc[0][1] = __builtin_amdgcn_mfma_f32_16x16x32_bf16(a0, b1, acc[0][1], 0, 0, 0);
                acc[0][2] = __builtin_amdgcn_mfma_f32_16x16x32_bf16(a0, b2, acc[0][2], 0, 0, 0);
                acc[0][3] = __builtin_amdgcn_mfma_f32_16x16x32_bf16(a0, b3, acc[0][3], 0, 0, 0);
                acc[1][0] = __builtin_amdgcn_mfma_f32_16x16x32_bf16(a1, b0, acc[1][0], 0, 0, 0);
                acc[1][1] = __builtin_amdgcn_mfma_f32_16x16x32_bf16(a1, b1, acc[1][1], 0, 0, 0);
                acc[1][2] = __builtin_amdgcn_mfma_f32_16x16x32_bf16(a1, b2, acc[1][2], 0, 0, 0);
                acc[1][3] = __builtin_amdgcn_mfma_f32_16x16x32_bf16(a1, b3, acc[1][3], 0, 0, 0);
            }
        }
    }

    // epilogue: C/D layout col=l16, row=quad*4+r ; local row = wm + mt*16 + quad*4 + r
#pragma unroll
    for (int mt = 0; mt < 2; ++mt) {
#pragma unroll
        for (int nt = 0; nt < 4; ++nt) {
            int col = nBase + wn + nt * 16 + l16;
            int trow = t0 + wm + mt * 16 + quad * 4;
            float bv = bias[col];
#pragma unroll
            for (int r = 0; r < 4; ++r) {
                long off = (long)z * sC1 + (long)(trow + r) * ldc + col;
                float v = acc[mt][nt][r] + bv;
                if (resid) v += resid[off];
                if (relu) v = fmaxf(v, 0.f);
                if (outBf) ((__bf16*)Cp)[off] = (__bf16)v;
                else       ((float*)Cp)[off] = v;
            }
        }
    }
}

// =====================================================================
// ======  Fused flash attention (QK^T -> softmax -> PV), DH=192  ======
// =====================================================================
__global__ __launch_bounds__(512) void flash_attn(
    const __bf16* __restrict__ qkv, __bf16* __restrict__ o, int T, float scl)
{
    int z = blockIdx.y;
    int b = z >> 1, h = z & 1;
    const __bf16* base = qkv + (long)b * T * 3 * CD + h * CDH;
    int qBase = blockIdx.x * 128;

    __shared__ __attribute__((aligned(16))) __bf16 Qs[128][200];
    __shared__ __attribute__((aligned(16))) __bf16 Ks[64][200];
    __shared__ __attribute__((aligned(16))) __bf16 Vt[192][72];
    __shared__ __attribute__((aligned(16))) __bf16 Ps[128][72];

    int tid  = threadIdx.x;
    int lane = tid & 63;
    int wave = tid >> 6;
    int quad = lane >> 4;
    int l16  = lane & 15;
    int wq   = wave * 16;

#pragma unroll
    for (int i = 0; i < 6; ++i) {
        int u = tid + i * 512;
        int r = u / 24, c = (u % 24) * 8;
        *(uint4*)(&Qs[r][c]) = *(const uint4*)(base + (long)(qBase + r) * 3 * CD + c);
    }

    f32x4 oacc[12];
#pragma unroll
    for (int j = 0; j < 12; ++j) oacc[j] = (f32x4){0.f, 0.f, 0.f, 0.f};
    float mrow[4], lrow[4];
#pragma unroll
    for (int r = 0; r < 4; ++r) { mrow[r] = -3.0e38f; lrow[r] = 0.f; }

    for (int kv0 = 0; kv0 < T; kv0 += 64) {
        __syncthreads();
#pragma unroll
        for (int i = 0; i < 3; ++i) {
            int u = tid + i * 512;
            int r = u / 24, c = (u % 24) * 8;
            *(uint4*)(&Ks[r][c]) = *(const uint4*)(base + CD + (long)(kv0 + r) * 3 * CD + c);
        }
#pragma unroll
        for (int i = 0; i < 3; ++i) {
            int u = tid + i * 512;
            int r = u / 24, c = (u % 24) * 8;
            uint4 pkt = *(const uint4*)(base + 2 * CD + (long)(kv0 + r) * 3 * CD + c);
            const __bf16* v8 = (const __bf16*)&pkt;
#pragma unroll
            for (int j = 0; j < 8; ++j) Vt[c + j][r] = v8[j];
        }
        __syncthreads();

        f32x4 s[4];
#pragma unroll
        for (int nt = 0; nt < 4; ++nt) s[nt] = (f32x4){0.f, 0.f, 0.f, 0.f};
#pragma unroll
        for (int ks = 0; ks < 6; ++ks) {
            bf16x8 aq = *(const bf16x8*)(&Qs[wq + l16][ks * 32 + quad * 8]);
#pragma unroll
            for (int nt = 0; nt < 4; ++nt) {
                bf16x8 bk = *(const bf16x8*)(&Ks[nt * 16 + l16][ks * 32 + quad * 8]);
                s[nt] = __builtin_amdgcn_mfma_f32_16x16x32_bf16(aq, bk, s[nt], 0, 0, 0);
            }
        }
        float alpha[4];
#pragma unroll
        for (int r = 0; r < 4; ++r) {
            float mx = -3.0e38f;
#pragma unroll
            for (int nt = 0; nt < 4; ++nt) {
                s[nt][r] *= scl;
                mx = fmaxf(mx, s[nt][r]);
            }
            mx = fmaxf(mx, __shfl_xor(mx, 1));
            mx = fmaxf(mx, __shfl_xor(mx, 2));
            mx = fmaxf(mx, __shfl_xor(mx, 4));
            mx = fmaxf(mx, __shfl_xor(mx, 8));
            float mnew = fmaxf(mrow[r], mx);
            alpha[r] = __expf(mrow[r] - mnew);
            mrow[r] = mnew;
            float rs = 0.f;
#pragma unroll
            for (int nt = 0; nt < 4; ++nt) {
                float e = __expf(s[nt][r] - mnew);
                s[nt][r] = e;
                rs += e;
            }
            rs += __shfl_xor(rs, 1);
            rs += __shfl_xor(rs, 2);
            rs += __shfl_xor(rs, 4);
            rs += __shfl_xor(rs, 8);
            lrow[r] = lrow[r] * alpha[r] + rs;
        }
#pragma unroll
        for (int r = 0; r < 4; ++r)
#pragma unroll
            for (int nt = 0; nt < 4; ++nt)
                Ps[wq + quad * 4 + r][nt * 16 + l16] = (__bf16)s[nt][r];
#pragma unroll
        for (int j = 0; j < 12; ++j)
#pragma unroll
            for (int r = 0; r < 4; ++r) oacc[j][r] *= alpha[r];
#pragma unroll
        for (int ks2 = 0; ks2 < 2; ++ks2) {
            bf16x8 ap = *(const bf16x8*)(&Ps[wq + l16][ks2 * 32 + quad * 8]);
#pragma unroll
            for (int nt = 0; nt < 12; ++nt) {
                bf16x8 bv = *(const bf16x8*)(&Vt[nt * 16 + l16][ks2 * 32 + quad * 8]);
                oacc[nt] = __builtin_amdgcn_mfma_f32_16x16x32_bf16(ap, bv, oacc[nt], 0, 0, 0);
            }
        }
    }

    __bf16* ob = o + ((long)b * T + qBase + wq + quad * 4) * CD + h * CDH + l16;
#pragma unroll
    for (int r = 0; r < 4; ++r) {
        float inv = 1.0f / lrow[r];
#pragma unroll
        for (int nt = 0; nt < 12; ++nt)
            ob[(long)r * CD + nt * 16] = (__bf16)(oacc[nt][r] * inv);
    }
}

// ---- LN: out32 = LN(a)*g+be ; bf16 padded copy ----
__global__ __launch_bounds__(CD) void ln_res(const float* __restrict__ a,
    const float* __restrict__ g, const float* __restrict__ be,
    float* __restrict__ out32, __bf16* __restrict__ outbf, int Tlog2)
{
    long r = blockIdx.x;
    int d = threadIdx.x;
    float v = a[r * CD + d];
    float s1 = v, s2 = v * v;
#pragma unroll
    for (int off = 32; off > 0; off >>= 1) {
        s1 += __shfl_down(s1, off);
        s2 += __shfl_down(s2, off);
    }
    __shared__ float sh1[CD / 64], sh2[CD / 64];
    int wv = d >> 6, ln = d & 63;
    if (ln == 0) { sh1[wv] = s1; sh2[wv] = s2; }
    __syncthreads();
    if (d == 0) {
        float t1 = 0.f, t2 = 0.f;
        for (int i = 0; i < CD / 64; ++i) { t1 += sh1[i]; t2 += sh2[i]; }
        sh1[0] = t1; sh2[0] = t2;
    }
    __syncthreads();
    float mean = sh1[0] * (1.0f / CD);
    float var  = sh2[0] * (1.0f / CD) - mean * mean;
    float res = (v - mean) * rsqrtf(var + 1e-5f) * g[d] + be[d];
    out32[r * CD + d] = res;
    int T = 1 << Tlog2;
    long bb = r >> Tlog2; int t = (int)(r & (T - 1));
    outbf[(bb * (T + 2) + t + 1) * CD + d] = (__bf16)res;
}

__global__ __launch_bounds__(CD) void f32_to_padbf16(const float* __restrict__ in,
    __bf16* __restrict__ out, int Tlog2)
{
    long r = blockIdx.x;
    int d = threadIdx.x;
    int T = 1 << Tlog2;
    long b = r >> Tlog2; int t = (int)(r & (T - 1));
    out[(b * (T + 2) + t + 1) * CD + d] = (__bf16)in[r * CD + d];
}

__global__ void zero_pads(__bf16* __restrict__ p, int Tp2, int C)
{
    int b = blockIdx.x >> 1;
    int which = blockIdx.x & 1;
    long row = (long)b * Tp2 + (which ? Tp2 - 1 : 0);
    for (int c = threadIdx.x; c < C; c += blockDim.x) p[row * C + c] = (__bf16)0.f;
}

__global__ __launch_bounds__(256) void tr_f32_bf16(const float* __restrict__ in,
    __bf16* __restrict__ out, int R, int C)
{
    __shared__ float t[32][33];
    int c0 = blockIdx.x * 32, r0 = blockIdx.y * 32;
    int tx = threadIdx.x & 31, ty = threadIdx.x >> 5;
#pragma unroll
    for (int i = 0; i < 4; ++i) {
        int rr = ty * 4 + i;
        int r = r0 + rr, c = c0 + tx;
        if (r < R && c < C) t[rr][tx] = in[(long)r * C + c];
    }
    __syncthreads();
#pragma unroll
    for (int i = 0; i < 4; ++i) {
        int cc = ty * 4 + i;
        int c = c0 + cc, r = r0 + tx;
        if (c < C && r < R) out[(long)c * R + r] = (__bf16)t[tx][cc];
    }
}

__global__ void convw_bf16(const float* __restrict__ w, __bf16* __restrict__ wt,
                           int O, int Cc)
{
    long total = (long)O * 3 * Cc;
    int KC = 3 * Cc;
    for (long i = (long)blockIdx.x * blockDim.x + threadIdx.x; i < total;
         i += (long)gridDim.x * blockDim.x) {
        int j = (int)(i % KC); long o = i / KC;
        int kk = j / Cc, c = j % Cc;
        wt[i] = (__bf16)w[(o * Cc + c) * 3 + kk];
    }
}

__global__ __launch_bounds__(CD) void embed_pe_kernel(const int* __restrict__ x,
    const float* __restrict__ emb, float* __restrict__ h)
{
    int bs = blockIdx.x;
    int d  = threadIdx.x;
    int s  = bs & (CS - 1);
    int tok = x[bs];
    int i = d >> 1;
    float ang = (float)s * powf(10000.0f, -2.0f * (float)i / (float)CD);
    float pe = (d & 1) ? cosf(ang) : sinf(ang);
    h[(size_t)bs * CD + d] = emb[(size_t)tok * CD + d] + pe;
}

__global__ __launch_bounds__(CS) void lenreg_kernel(const int* __restrict__ y,
    int* __restrict__ idx, int* __restrict__ totals)
{
    __shared__ int ends[CS];
    int b = blockIdx.x, tid = threadIdx.x;
    if (tid == 0) {
        int acc = 0;
        for (int s = 0; s < CS; ++s) { acc += y[b * CS + s]; ends[s] = acc; }
    }
    __syncthreads();
    for (int t = tid; t < CLOUT; t += CS) idx[b * CLOUT + t] = CS - 1;
    if (tid == 0) totals[b] = ends[CS - 1];
    __syncthreads();
    int st = (tid == 0) ? 0 : ends[tid - 1];
    int en = ends[tid];
    for (int t = st; t < en; ++t) idx[b * CLOUT + t] = tid;
}

__global__ __launch_bounds__(CD) void gather_dual(const float* __restrict__ hph,
    const int* __restrict__ idx, const int* __restrict__ tot,
    float* __restrict__ h32, __bf16* __restrict__ hbf, int chunkBase)
{
    int rl = blockIdx.x;
    int rg = chunkBase + rl;
    int b = rg >> 10, t = rg & (CLOUT - 1);
    int d = threadIdx.x;
    int src = idx[rg];
    float v = (t < tot[b]) ? hph[((long)b * CS + src) * CD + d] : 0.f;
    h32[(long)rl * CD + d] = v;
    long bl = rl >> 10; int tl = rl & (CLOUT - 1);
    hbf[(bl * (CLOUT + 2) + tl + 1) * CD + d] = (__bf16)v;
}

// =====================================================================
// ===============  bf16 path driver  ==================================
// =====================================================================

static inline void mm(hipStream_t st, const __bf16* A, long lda, long sA1, long sA2,
    const __bf16* Bt, long ldb, long sB1, long sB2, const float* bias,
    const float* resid, void* C, long ldc, long sC1, long sC2, int M, int N, int K,
    int nz, int zdiv, int relu, int outBf, float scale)
{
    dim3 g((N + 127) / 128, M / 128, nz), b(256, 1, 1);
    hipLaunchKernelGGL(mm_bf16, g, b, 0, st, A, lda, sA1, sA2, Bt, ldb, sB1, sB2,
                       bias, resid, C, ldc, sC1, sC2, M, N, K, zdiv, relu, outBf, scale);
}

struct Scr {
    float *h32, *x32, *tmp32;
    __bf16 *hbf, *xbf, *qkv, *c1p, *o;
};

static size_t scr_layout(char* base, int NB, int T, Scr* s)
{
    auto align = [](size_t v) { return (v + 255) & ~(size_t)255; };
    size_t off = 0;
    long Tp2 = T + 2;
    if (s) s->h32 = (float*)(base + off);
    off = align(off + (size_t)NB * T * CD * 4);
    if (s) s->x32 = (float*)(base + off);
    off = align(off + (size_t)NB * T * CD * 4);
    if (s) s->tmp32 = (float*)(base + off);
    off = align(off + (size_t)NB * T * CD * 4);
    if (s) s->hbf = (__bf16*)(base + off);
    off = align(off + (size_t)NB * Tp2 * CD * 2);
    if (s) s->xbf = (__bf16*)(base + off);
    off = align(off + (size_t)NB * Tp2 * CD * 2);
    if (s) s->qkv = (__bf16*)(base + off);
    off = align(off + (size_t)NB * T * 3 * CD * 2);
    if (s) s->c1p = (__bf16*)(base + off);
    off = align(off + (size_t)NB * Tp2 * CDF * 2);
    if (s) s->o = (__bf16*)(base + off);
    off = align(off + (size_t)NB * T * CD * 2);
    return off;
}

// per-layer bf16 weight offsets (elements)
constexpr long W_QKV = 0;
constexpr long W_OUT = 442368;
constexpr long W_C1  = 589824;
constexpr long W_C2  = 2359296;
constexpr long WLAYER = 4128768;
constexpr long WSTACK = 6 * WLAYER;
constexpr long WTOT   = WSTACK + 30720;

static void convert_stack_weights(hipStream_t st, __bf16* wbuf,
    const float* qkv_w, const float* out_w, const float* c1w, const float* c2w)
{
    for (int l = 0; l < CL; ++l) {
        __bf16* wl = wbuf + (long)l * WLAYER;
        hipLaunchKernelGGL(tr_f32_bf16, dim3(36, 12), dim3(256), 0, st,
                           qkv_w + (long)l * CD * 3 * CD, wl + W_QKV, CD, 3 * CD);
        hipLaunchKernelGGL(tr_f32_bf16, dim3(12, 12), dim3(256), 0, st,
                           out_w + (long)l * CD * CD, wl + W_OUT, CD, CD);
        hipLaunchKernelGGL(convw_bf16, dim3(2048), dim3(256), 0, st,
                           c1w + (long)l * CDF * CD * 3, wl + W_C1, CDF, CD);
        hipLaunchKernelGGL(convw_bf16, dim3(2048), dim3(256), 0, st,
                           c2w + (long)l * CD * CDF * 3, wl + W_C2, CD, CDF);
    }
}

static void fft_block_bf16(hipStream_t st, const Scr& S, int NBc, int T, int tlog2,
    float* h32, const __bf16* wl,
    const float* qkv_b, const float* out_b,
    const float* g1, const float* b1, const float* c1b, const float* c2b,
    const float* g2, const float* b2)
{
    const int M = NBc * T;
    const long Tp2 = T + 2;
    const float scl = 1.0f / sqrtf((float)CDH);

    // qkv = h @ Wqkv + b
    mm(st, S.hbf + CD, CD, Tp2 * CD, 0, wl + W_QKV, CD, 0, 0, qkv_b, nullptr,
       S.qkv, 3 * CD, (long)T * 3 * CD, 0, T, 3 * CD, CD, NBc, 1, 0, 1, 1.f);

    // fused attention
    hipLaunchKernelGGL(flash_attn, dim3(T / 128, NBc * CH), dim3(512), 0, st,
                       S.qkv, S.o, T, scl);

    // tmp = o @ Wout + b + h (residual fused)
    mm(st, S.o, CD, 0, 0, wl + W_OUT, CD, 0, 0, out_b, h32,
       S.tmp32, CD, 0, 0, M, CD, CD, 1, 1, 0, 0, 1.f);

    // x = LN(tmp)
    hipLaunchKernelGGL(ln_res, dim3(M), dim3(CD), 0, st,
                       S.tmp32, g1, b1, S.x32, S.xbf, tlog2);

    // conv1: relu(conv(x)) -> c1p rows 1..T (bf16), windowed staging
    hipLaunchKernelGGL(conv_mfma, dim3(CDF / 128, T / 128, NBc), dim3(512), 0, st,
                       S.xbf, wl + W_C1, c1b, nullptr,
                       (void*)(S.c1p + CDF), (long)CDF, Tp2 * CDF,
                       T, (int)Tp2, CD, CDF, 1, 1);

    // conv2 + resid -> tmp32 (fp32)
    hipLaunchKernelGGL(conv_mfma, dim3(CD / 128, T / 128, NBc), dim3(512), 0, st,
                       S.c1p, wl + W_C2, c2b, S.x32,
                       S.tmp32, (long)CD, (long)T * CD,
                       T, (int)Tp2, CDF, CD, 0, 0);

    // h = LN(tmp)
    hipLaunchKernelGGL(ln_res, dim3(M), dim3(CD), 0, st,
                       S.tmp32, g2, b2, h32, S.hbf, tlog2);
}

extern "C" void kernel_launch(void* const* d_in, const int* in_sizes, int n_in,
                              void* d_out, int out_size, void* d_ws, size_t ws_size,
                              hipStream_t stream)
{
    (void)in_sizes; (void)out_size;

    const int* x = (const int*)d_in[0];
    const int* y = (const int*)d_in[1];
    const float* P[40];
    for (int i = 0; i < n_in && i < 40; ++i) P[i] = (const float*)d_in[i];

    size_t wbufB  = ((size_t)WTOT * 2 + 255) & ~(size_t)255;
    size_t hphB   = ((size_t)CB * CS * CD * 4 + 255) & ~(size_t)255;
    size_t idxB   = (((size_t)CB * CLOUT + CB) * 4 + 255) & ~(size_t)255;
    size_t fixedB = wbufB + hphB + idxB;

    size_t scrB = (ws_size > fixedB) ? (ws_size - fixedB) : 0;

    int NBmel = 1;
    for (int cand = 16; cand >= 1; cand >>= 1)
        if (scr_layout(nullptr, cand, CLOUT, nullptr) <= scrB) { NBmel = cand; break; }

    int NBph = 1;
    for (int cand = 16; cand >= 1; cand >>= 1)
        if (scr_layout(nullptr, cand, CS, nullptr) <= scrB) { NBph = cand; break; }

    char* base = (char*)d_ws;
    __bf16* wbuf = (__bf16*)base;
    float*  hPh  = (float*)(base + wbufB);
    int*    idxb = (int*)(base + wbufB + hphB);
    int*    totb = idxb + (long)CB * CLOUT;
    char*   scrbase = base + fixedB;

    // ================= phoneme encoder =================
    convert_stack_weights(stream, wbuf, P[3], P[5], P[9], P[11]);

    Scr Sp; scr_layout(scrbase, NBph, CS, &Sp);
    hipLaunchKernelGGL(zero_pads, dim3(NBph * 2), dim3(256), 0, stream, Sp.hbf, CS + 2, CD);
    hipLaunchKernelGGL(zero_pads, dim3(NBph * 2), dim3(256), 0, stream, Sp.xbf, CS + 2, CD);
    hipLaunchKernelGGL(zero_pads, dim3(NBph * 2), dim3(256), 0, stream, Sp.c1p, CS + 2, CDF);

    hipLaunchKernelGGL(embed_pe_kernel, dim3(CB * CS), dim3(CD), 0, stream, x, P[2], hPh);

    for (int c = 0; c < CB / NBph; ++c) {
        float* hch = hPh + (long)c * NBph * CS * CD;
        hipLaunchKernelGGL(f32_to_padbf16, dim3(NBph * CS), dim3(CD), 0, stream,
                           hch, Sp.hbf, 7);
        for (int l = 0; l < CL; ++l)
            fft_block_bf16(stream, Sp, NBph, CS, 7, hch, wbuf + (long)l * WLAYER,
                           P[4] + (long)l * 3 * CD, P[6] + (long)l * CD,
                           P[7] + (long)l * CD, P[8] + (long)l * CD,
                           P[10] + (long)l * CDF, P[12] + (long)l * CD,
                           P[13] + (long)l * CD, P[14] + (long)l * CD);
    }

    // ================= length regulation =================
    hipLaunchKernelGGL(lenreg_kernel, dim3(CB), dim3(CS), 0, stream, y, idxb, totb);

    // ================= mel decoder =================
    convert_stack_weights(stream, wbuf, P[15], P[17], P[21], P[23]);
    hipLaunchKernelGGL(tr_f32_bf16, dim3(3, 12), dim3(256), 0, stream,
                       P[37], wbuf + WSTACK, CD, CNM);

    Scr Sm; scr_layout(scrbase, NBmel, CLOUT, &Sm);
    hipLaunchKernelGGL(zero_pads, dim3(NBmel * 2), dim3(256), 0, stream, Sm.hbf, CLOUT + 2, CD);
    hipLaunchKernelGGL(zero_pads, dim3(NBmel * 2), dim3(256), 0, stream, Sm.xbf, CLOUT + 2, CD);
    hipLaunchKernelGGL(zero_pads, dim3(NBmel * 2), dim3(256), 0, stream, Sm.c1p, CLOUT + 2, CDF);

    for (int c = 0; c < CB / NBmel; ++c) {
        hipLaunchKernelGGL(gather_dual, dim3(NBmel * CLOUT), dim3(CD), 0, stream,
                           hPh, idxb, totb, Sm.h32, Sm.hbf, c * NBmel * CLOUT);
        for (int l = 0; l < CL; ++l)
            fft_block_bf16(stream, Sm, NBmel, CLOUT, 10, Sm.h32, wbuf + (long)l * WLAYER,
                           P[16] + (long)l * 3 * CD, P[18] + (long)l * CD,
                           P[19] + (long)l * CD, P[20] + (long)l * CD,
                           P[22] + (long)l * CDF, P[24] + (long)l * CD,
                           P[25] + (long)l * CD, P[26] + (long)l * CD);
        // final projection for this chunk
        mm(stream, Sm.hbf + CD, CD, (long)(CLOUT + 2) * CD, 0,
           wbuf + WSTACK, CD, 0, 0, P[38], nullptr,
           (float*)d_out + (long)c * NBmel * CLOUT * CNM, CNM, (long)CLOUT * CNM, 0,
           CLOUT, CNM, CD, NBmel, 1, 0, 0, 1.f);
    }
}